// Round 5
// baseline (77.776 us; speedup 1.0000x reference)
//
#include <hip/hip_runtime.h>
#include <stdint.h>
#include <math.h>

// ---------------------------------------------------------------------------
// SparseExplorerRouting, round 8.
//
// Carried facts (R1-R3, R5 PASSED, absmax 0; R4/R6/R7 regressed, reverted):
//   * jax_threefry_partitionable=True counter scheme; key(42) -> (0,42);
//     walk (v,w) = split child v*5+w; per-step children ctr (0,{0,1,2}).
//   * output int32 {flags[1024], sum_aborts, sum_restarts}.
//   * f64 analog math proxy for the f32 reference passes with margin.
//   * E-table argmax(E/w) trick, w=-log(u); minE<e^0.5 == min_sim<0.1.
//   * R4/R6 lesson: walk restructures lose; R5 walk body (42.2us) is the
//     schedule to keep. R7 lesson: f64-MFMA band loses (tiny tile, huge K,
//     1 block/CU, dependent MFMA chain); scalar R5 band is the keeper.
//   * Walk VALU decomposition (from VALUBusy 70%): ~1760 cy/wave-step;
//     threefry fold + f64 log ~= 55-60% of it, and the random bits are
//     STATE-INDEPENDENT (depend only on walk,step,at,lane). Data makes
//     attempt 0 always pass the cycle check (tr ~= 1 - 3e-11).
//
// Round 8 changes:
//   * W-table: w = -log(u) for attempt 0 of every (walk,step,lane), 21 MB
//     in workspace, produced by 4 EXTRA rng waves appended to each band
//     block (768 thr; rng runs after the single barrier, overlapping band
//     stalls). Bit-identical doubles to the inline computation.
//   * walk_tab_kernel = R5 body verbatim, but attempt 0 loads its w row
//     (512 B coalesced, issued with the Ej row); attempts >=1 (never taken
//     on this data) compute inline exactly as before.
//   * Tiers: ws >= sumsq+Etab+W -> fast+table; >= sumsq+Etab -> R5 path;
//     else rowsq+walk_ref.
// ---------------------------------------------------------------------------

#define HID        1024
#define NUM_WALKS  5
#define WALK_LEN   8
#define HALF_WIN   16
#define E_THRESH   1.6487212707001282   // exp(0.5) = exp(5 * BIRTH_DEATH_EPS)

#define CENTERS    16                   // centers per band block
#define SROWS      32                   // staged rows = CENTERS + 16 halo

__device__ __forceinline__ void tf2x32(uint32_t k0, uint32_t k1,
                                       uint32_t& x0, uint32_t& x1) {
  uint32_t ks2 = k0 ^ k1 ^ 0x1BD11BDAu;
  x0 += k0; x1 += k1;
#define TFR(r) { x0 += x1; x1 = (x1 << (r)) | (x1 >> (32 - (r))); x1 ^= x0; }
  TFR(13) TFR(15) TFR(26) TFR(6)
  x0 += k1;  x1 += ks2 + 1u;
  TFR(17) TFR(29) TFR(16) TFR(24)
  x0 += ks2; x1 += k0 + 2u;
  TFR(13) TFR(15) TFR(26) TFR(6)
  x0 += k0;  x1 += k1 + 3u;
  TFR(17) TFR(29) TFR(16) TFR(24)
  x0 += k1;  x1 += ks2 + 4u;
  TFR(13) TFR(15) TFR(26) TFR(6)
  x0 += ks2; x1 += k0 + 5u;
#undef TFR
}

__device__ __forceinline__ uint32_t tf_fold(uint32_t k0, uint32_t k1,
                                            uint32_t c0, uint32_t c1) {
  tf2x32(k0, k1, c0, c1);
  return c0 ^ c1;
}

// w = -log(u) from the attempt bits -- EXACT copy of the walk's inline math.
__device__ __forceinline__ double w_from_bits(uint32_t bits) {
  const uint32_t fb = (bits >> 9) | 0x3f800000u;
  const float    ff = __uint_as_float(fb) - 1.0f;
  const float    u  = (ff > 0.0f) ? ff : 1.1754943508222875e-38f;
  return -log((double)u);
}

// ---- fused band + rowsq + d_out zeroing + rng W-table ----------------------
// Waves 0..7: R5 band (stage 32 rows in LDS w/ sumsq, then 2 centers/wave,
// d-loop fully unrolled). Waves 8..11: W-table rng (state-independent).
__global__ __launch_bounds__(768) void band_fused_kernel(
    const float* __restrict__ H, double* __restrict__ sumsq,
    double* __restrict__ E, double* __restrict__ Wtab, int nwalks,
    int* __restrict__ out, int out_n, int seq_len) {
  __shared__ __align__(16) float  tile[SROWS][HID];   // 128 KB
  __shared__ double ssq[SROWS];

  if (blockIdx.x == 0) {                 // fold d_out zeroing in (dispatch
    for (int t = threadIdx.x; t < out_n; t += blockDim.x) out[t] = 0;
  }                                      // ordering guarantees walk sees 0s

  int wg = blockIdx.x;
  {
    const int nwg = gridDim.x;           // bijective XCD swizzle (nwg%8==0)
    if ((nwg & 7) == 0) wg = (wg & 7) * (nwg >> 3) + (wg >> 3);
  }
  const int wid  = (int)(threadIdx.x >> 6);   // 0..11
  const int lane = (int)(threadIdx.x & 63);
  const int i0   = wg * CENTERS;
  const float4* __restrict__ H4 = (const float4*)H;

  // ---- stage 4 rows per band wave + sumsq (same order as old rowsq) ----
  if (wid < 8) {
#pragma unroll
    for (int rr = 0; rr < 4; ++rr) {
      const int local = wid * 4 + rr;    // wave-uniform
      const int row   = i0 + local;
      if (row < seq_len) {
        const float4* src = H4 + ((size_t)row << 8);
        float4* dst = (float4*)&tile[local][0];
        double acc = 0.0;
#pragma unroll
        for (int k = 0; k < 4; ++k) {
          float4 x = src[lane + (k << 6)];
          dst[lane + (k << 6)] = x;
          acc += (double)x.x * x.x + (double)x.y * x.y
               + (double)x.z * x.z + (double)x.w * x.w;
        }
#pragma unroll
        for (int off = 32; off; off >>= 1) acc += __shfl_xor(acc, off);
        if (lane == 0) {
          ssq[local] = acc;
          if (local < CENTERS) sumsq[row] = acc;   // row owned by 1 block
        }
      }
    }
  }
  __syncthreads();

  if (wid >= 8) {
    // ---- rng waves: fill W[walk][step][lane] = w for attempt 0 ----
    if (Wtab != nullptr) {
      const int g      = (int)blockIdx.x * 4 + (wid - 8);
      const int stride = (int)gridDim.x * 4;
      for (int wv = g; wv < nwalks; wv += stride) {
        uint32_t k0 = 0u, k1 = (uint32_t)wv;
        tf2x32(0u, 42u, k0, k1);
        k0 = __builtin_amdgcn_readfirstlane(k0);
        k1 = __builtin_amdgcn_readfirstlane(k1);
        for (int s = 0; s < WALK_LEN; ++s) {
          uint32_t nk0 = 0u, nk1 = 0u; tf2x32(k0, k1, nk0, nk1);
          uint32_t ks0 = 0u, ks1 = 1u; tf2x32(k0, k1, ks0, ks1);
          uint32_t s0  = 0u, s1  = 0u; tf2x32(ks0, ks1, s0, s1);  // at = 0
          const uint32_t bits = tf_fold(s0, s1, 0u, (uint32_t)lane);
          Wtab[(((size_t)wv * WALK_LEN + s) << 6) + lane] = w_from_bits(bits);
          k0 = __builtin_amdgcn_readfirstlane(nk0);
          k1 = __builtin_amdgcn_readfirstlane(nk1);
        }
      }
    }
    return;
  }

  // ---- 2 centers per band wave, 16 forward dots each, from LDS ----
#pragma unroll
  for (int cc = 0; cc < 2; ++cc) {
    const int cl = wid * 2 + cc;         // 0..15, wave-uniform
    const int i  = i0 + cl;
    if (i >= seq_len) continue;

    double a[16];
    {
      const float4* rc = (const float4*)&tile[cl][0];
#pragma unroll
      for (int k = 0; k < 4; ++k) {
        float4 x = rc[lane + (k << 6)];
        a[4*k+0] = x.x; a[4*k+1] = x.y; a[4*k+2] = x.z; a[4*k+3] = x.w;
      }
    }
    const double ni = sqrt(ssq[cl]) + 1e-8;

    // d-loop fully unrolled: p[] indices static -> registers, no scratch.
    // Halo garbage (i+d >= seq_len) stays segregated per-d and never
    // reaches the guarded write. Bit-identical valid E.
    double p[16];
#pragma unroll
    for (int d = 0; d < 16; ++d) p[d] = 0.0;
#pragma unroll
    for (int d = 1; d <= 16; ++d) {
      const float4* rb = (const float4*)&tile[cl + d][0];
#pragma unroll
      for (int k = 0; k < 4; ++k) {
        float4 x = rb[lane + (k << 6)];
        p[d-1] += a[4*k+0] * (double)x.x + a[4*k+1] * (double)x.y
                + a[4*k+2] * (double)x.z + a[4*k+3] * (double)x.w;
      }
    }

    // multi-value reduce-scatter: value bit3..0 <- lane bit5..2
#pragma unroll
    for (int v = 0; v < 8; ++v) {                     // stage xor 32
      double send = (lane & 32) ? p[v] : p[v+8];
      double recv = __shfl_xor(send, 32);
      double mine = (lane & 32) ? p[v+8] : p[v];
      p[v] = mine + recv;
    }
#pragma unroll
    for (int v = 0; v < 4; ++v) {                     // stage xor 16
      double send = (lane & 16) ? p[v] : p[v+4];
      double recv = __shfl_xor(send, 16);
      double mine = (lane & 16) ? p[v+4] : p[v];
      p[v] = mine + recv;
    }
#pragma unroll
    for (int v = 0; v < 2; ++v) {                     // stage xor 8
      double send = (lane & 8) ? p[v] : p[v+2];
      double recv = __shfl_xor(send, 8);
      double mine = (lane & 8) ? p[v+2] : p[v];
      p[v] = mine + recv;
    }
    {                                                 // stage xor 4
      double send = (lane & 4) ? p[0] : p[1];
      double recv = __shfl_xor(send, 4);
      double mine = (lane & 4) ? p[1] : p[0];
      p[0] = mine + recv;
    }
    p[0] += __shfl_xor(p[0], 2);                      // stage xor 2
    p[0] += __shfl_xor(p[0], 1);                      // stage xor 1

    const int v = ((lane >> 2) & 1) | (((lane >> 3) & 1) << 1)
                | (((lane >> 4) & 1) << 2) | (((lane >> 5) & 1) << 3);
    const int d = v + 1;
    if ((lane & 3) == 0 && i + d < seq_len) {
      const double s  = p[0] / (ni * (sqrt(ssq[cl + d]) + 1e-8));
      const double Ev = exp(5.0 * s);
      E[(size_t)i * 33 + 16 + d]       = Ev;
      E[(size_t)(i + d) * 33 + 16 - d] = Ev;
    }
  }
}

// ---- per-row sum of squares (f64) + d_out zeroing (tier-3 only) ------------
__global__ __launch_bounds__(256) void rowsq_kernel(
    const float* __restrict__ H, double* __restrict__ sumsq,
    int* __restrict__ out, int out_n, int seq_len) {
  if (blockIdx.x == 0) {
    for (int t = threadIdx.x; t < out_n; t += 256) out[t] = 0;
  }
  const int row  = (int)((blockIdx.x * blockDim.x + threadIdx.x) >> 6);
  const int lane = threadIdx.x & 63;
  if (row >= seq_len) return;
  const float4* r = (const float4*)(H + (size_t)row * HID);
  double acc = 0.0;
#pragma unroll
  for (int k = 0; k < 4; ++k) {
    float4 x = r[lane + (k << 6)];
    acc += (double)x.x * x.x + (double)x.y * x.y
         + (double)x.z * x.z + (double)x.w * x.w;
  }
#pragma unroll
  for (int off = 32; off; off >>= 1) acc += __shfl_xor(acc, off);
  if (lane == 0) sumsq[row] = acc;
}

// ---- walk kernel, W-table variant: R5 body + attempt-0 w load --------------
__global__ __launch_bounds__(256) void walk_tab_kernel(
    const double* __restrict__ E, const double* __restrict__ sumsq,
    const double* __restrict__ Wtab, const int* __restrict__ viol,
    int* __restrict__ out, int nv, int seq_len) {
  int wave = (int)((blockIdx.x * blockDim.x + threadIdx.x) >> 6);
  const int lane = threadIdx.x & 63;
  if (wave >= nv * NUM_WALKS) return;
  wave = __builtin_amdgcn_readfirstlane(wave);
  const int v     = wave / NUM_WALKS;
  const int start = viol[v];

  uint32_t key0 = 0u, key1 = (uint32_t)wave;
  tf2x32(0u, 42u, key0, key1);
  key0 = __builtin_amdgcn_readfirstlane(key0);
  key1 = __builtin_amdgcn_readfirstlane(key1);

  int    cur = start, prev = start, plen = 1;
  double minE = 1e300;
  bool   detected = false;
  int    aborts = 0, restarts = 0;
  // carried |h|^2 of prev / cur (identical doubles to sumsq[] entries)
  double na_d = sumsq[start], nb_d = na_d;

  for (int step = 0; step < WALK_LEN; ++step) {
    // key, k_samp, k_restart = split(key,3) -- scalar (SALU) chain
    uint32_t nk0 = 0u, nk1 = 0u; tf2x32(key0, key1, nk0, nk1);
    uint32_t ks0 = 0u, ks1 = 1u; tf2x32(key0, key1, ks0, ks1);
    uint32_t kr0 = 0u, kr1 = 2u; tf2x32(key0, key1, kr0, kr1);

    const int  myidx   = cur - HALF_WIN + lane;
    const bool myvalid = (lane < 33) && (lane != HALF_WIN) &&
                         (myidx >= 0) && (myidx < seq_len);
    const int  clipped = myidx < 0 ? 0 : (myidx >= seq_len ? seq_len - 1 : myidx);
    const double Ej = E[(size_t)cur * 33 + (lane < 33 ? lane : 0)];
    const double sq_win = sumsq[clipped];   // window |h|^2, issued with Ej
    const double w0 = Wtab[(((size_t)wave * WALK_LEN + step) << 6) + lane];

    bool found = false; int fails = 0, p = 0, cand = 0;
    double nc_d = 0.0;
    for (int at = 0; at < 3; ++at) {
      double w;
      if (at == 0) {
        w = w0;                          // precomputed, bit-identical
      } else {                           // cold path (never taken on data)
        uint32_t s0 = 0u, s1 = (uint32_t)at; tf2x32(ks0, ks1, s0, s1);
        const uint32_t bits = tf_fold(s0, s1, 0u, (uint32_t)lane);
        w = w_from_bits(bits);
      }
      double f; int bi;
      if (myvalid) {
        f  = Ej / w;          // argmax(E/w) == argmax(5*sim + gumbel)
        bi = lane;
      } else { f = -1.0; bi = 1000; }
#pragma unroll
      for (int off = 32; off; off >>= 1) {
        const double of = __shfl_xor(f, off);
        const int    oi = __shfl_xor(bi, off);
        if (of > f || (of == f && oi < bi)) { f = of; bi = oi; }
      }
      p    = bi;
      cand = cur - HALF_WIN + p;
      nc_d = __shfl(sq_win, p);     // == sumsq[cand], no dependent load
      bool ok;
      if (plen < 2) ok = true;
      else {
        const float na = (float)na_d, nb = (float)nb_d, nc = (float)nc_d;
        const float tr  = (na * nb * nc) /
                          ((na + 1e-8f) * (nb + 1e-8f) * (nc + 1e-8f));
        const float dev = fabsf(tr - rintf(tr));
        ok = (dev <= 0.1f) && (tr <= 1.5f);
      }
      if (ok) { found = true; break; }
      ++fails;
    }
    aborts += fails;

    if (found) {
      const double Ewin = __shfl(Ej, p);
      minE = fmin(minE, Ewin);
      const bool closed = (cand == start) && (plen > 2);
      prev = cur; cur = cand; plen += 1;
      na_d = nb_d; nb_d = nc_d;
      if (closed) { if (minE < E_THRESH) detected = true; break; }
    } else {
      ++restarts;
      uint32_t h0 = 0u, h1 = 0u; tf2x32(kr0, kr1, h0, h1);
      uint32_t l0 = 0u, l1 = 1u; tf2x32(kr0, kr1, l0, l1);
      const uint32_t hi = tf_fold(h0, h1, 0u, 0u);
      const uint32_t lo = tf_fold(l0, l1, 0u, 0u);
      const uint32_t span = (uint32_t)nv;
      uint32_t mult = (65536u % span); mult = (mult * mult) % span;
      const uint32_t r = ((hi % span) * mult + (lo % span)) % span;
      const int node = viol[r];
      cur = node; prev = node; plen = 1;
      na_d = sumsq[node]; nb_d = na_d;   // rare path, load tolerated
    }
    key0 = __builtin_amdgcn_readfirstlane(nk0);
    key1 = __builtin_amdgcn_readfirstlane(nk1);
  }

  if (lane == 0) {
    if (detected)      atomicOr(&out[v], 1);
    if (aborts != 0)   atomicAdd(&out[nv], aborts);
    if (restarts != 0) atomicAdd(&out[nv + 1], restarts);
  }
}

// ---- walk kernel: R5 body VERBATIM (tier-2, no W table) --------------------
__global__ __launch_bounds__(256) void walk_fast_kernel(
    const double* __restrict__ E, const double* __restrict__ sumsq,
    const int* __restrict__ viol, int* __restrict__ out,
    int nv, int seq_len) {
  int wave = (int)((blockIdx.x * blockDim.x + threadIdx.x) >> 6);
  const int lane = threadIdx.x & 63;
  if (wave >= nv * NUM_WALKS) return;
  wave = __builtin_amdgcn_readfirstlane(wave);
  const int v     = wave / NUM_WALKS;
  const int start = viol[v];

  uint32_t key0 = 0u, key1 = (uint32_t)wave;
  tf2x32(0u, 42u, key0, key1);
  key0 = __builtin_amdgcn_readfirstlane(key0);
  key1 = __builtin_amdgcn_readfirstlane(key1);

  int    cur = start, prev = start, plen = 1;
  double minE = 1e300;
  bool   detected = false;
  int    aborts = 0, restarts = 0;
  double na_d = sumsq[start], nb_d = na_d;

  for (int step = 0; step < WALK_LEN; ++step) {
    uint32_t nk0 = 0u, nk1 = 0u; tf2x32(key0, key1, nk0, nk1);
    uint32_t ks0 = 0u, ks1 = 1u; tf2x32(key0, key1, ks0, ks1);
    uint32_t kr0 = 0u, kr1 = 2u; tf2x32(key0, key1, kr0, kr1);

    const int  myidx   = cur - HALF_WIN + lane;
    const bool myvalid = (lane < 33) && (lane != HALF_WIN) &&
                         (myidx >= 0) && (myidx < seq_len);
    const int  clipped = myidx < 0 ? 0 : (myidx >= seq_len ? seq_len - 1 : myidx);
    const double Ej = E[(size_t)cur * 33 + (lane < 33 ? lane : 0)];
    const double sq_win = sumsq[clipped];

    bool found = false; int fails = 0, p = 0, cand = 0;
    double nc_d = 0.0;
    for (int at = 0; at < 3; ++at) {
      uint32_t s0 = 0u, s1 = (uint32_t)at; tf2x32(ks0, ks1, s0, s1);
      double f; int bi;
      if (myvalid) {
        const uint32_t bits = tf_fold(s0, s1, 0u, (uint32_t)lane);
        const double   w    = w_from_bits(bits);
        f  = Ej / w;
        bi = lane;
      } else { f = -1.0; bi = 1000; }
#pragma unroll
      for (int off = 32; off; off >>= 1) {
        const double of = __shfl_xor(f, off);
        const int    oi = __shfl_xor(bi, off);
        if (of > f || (of == f && oi < bi)) { f = of; bi = oi; }
      }
      p    = bi;
      cand = cur - HALF_WIN + p;
      nc_d = __shfl(sq_win, p);
      bool ok;
      if (plen < 2) ok = true;
      else {
        const float na = (float)na_d, nb = (float)nb_d, nc = (float)nc_d;
        const float tr  = (na * nb * nc) /
                          ((na + 1e-8f) * (nb + 1e-8f) * (nc + 1e-8f));
        const float dev = fabsf(tr - rintf(tr));
        ok = (dev <= 0.1f) && (tr <= 1.5f);
      }
      if (ok) { found = true; break; }
      ++fails;
    }
    aborts += fails;

    if (found) {
      const double Ewin = __shfl(Ej, p);
      minE = fmin(minE, Ewin);
      const bool closed = (cand == start) && (plen > 2);
      prev = cur; cur = cand; plen += 1;
      na_d = nb_d; nb_d = nc_d;
      if (closed) { if (minE < E_THRESH) detected = true; break; }
    } else {
      ++restarts;
      uint32_t h0 = 0u, h1 = 0u; tf2x32(kr0, kr1, h0, h1);
      uint32_t l0 = 0u, l1 = 1u; tf2x32(kr0, kr1, l0, l1);
      const uint32_t hi = tf_fold(h0, h1, 0u, 0u);
      const uint32_t lo = tf_fold(l0, l1, 0u, 0u);
      const uint32_t span = (uint32_t)nv;
      uint32_t mult = (65536u % span); mult = (mult * mult) % span;
      const uint32_t r = ((hi % span) * mult + (lo % span)) % span;
      const int node = viol[r];
      cur = node; prev = node; plen = 1;
      na_d = sumsq[node]; nb_d = na_d;
    }
    key0 = __builtin_amdgcn_readfirstlane(nk0);
    key1 = __builtin_amdgcn_readfirstlane(nk1);
  }

  if (lane == 0) {
    if (detected)      atomicOr(&out[v], 1);
    if (aborts != 0)   atomicAdd(&out[nv], aborts);
    if (restarts != 0) atomicAdd(&out[nv + 1], restarts);
  }
}

// ---- fallback: round-1 in-walk dot kernel (only if ws too small) -----------
__global__ __launch_bounds__(256) void walk_ref_kernel(
    const float* __restrict__ H, const int* __restrict__ viol,
    const double* __restrict__ sumsq, int* __restrict__ out,
    int nv, int seq_len) {
  const int wave = (int)((blockIdx.x * blockDim.x + threadIdx.x) >> 6);
  const int lane = threadIdx.x & 63;
  if (wave >= nv * NUM_WALKS) return;
  const int v     = wave / NUM_WALKS;
  const int start = viol[v];
  uint32_t key0 = 0u, key1 = (uint32_t)wave;
  tf2x32(0u, 42u, key0, key1);
  const float4* __restrict__ H4 = (const float4*)H;
  int    cur = start, prev = start, plen = 1;
  double min_sim = 1e9;
  bool   detected = false;
  int    aborts = 0, restarts = 0;
  for (int step = 0; step < WALK_LEN; ++step) {
    uint32_t nk0 = 0u, nk1 = 0u; tf2x32(key0, key1, nk0, nk1);
    uint32_t ks0 = 0u, ks1 = 1u; tf2x32(key0, key1, ks0, ks1);
    uint32_t kr0 = 0u, kr1 = 2u; tf2x32(key0, key1, kr0, kr1);
    const double ncur = sqrt(sumsq[cur]) + 1e-8;
    double a[16];
    {
      const float4* rc = H4 + ((size_t)cur << 8);
#pragma unroll
      for (int k = 0; k < 4; ++k) {
        float4 x = rc[lane + (k << 6)];
        a[4*k+0] = x.x; a[4*k+1] = x.y; a[4*k+2] = x.z; a[4*k+3] = x.w;
      }
    }
    double my_sim = 0.0;
    for (int jj = 0; jj < 33; ++jj) {
      const int idx = cur - HALF_WIN + jj;
      if (jj == HALF_WIN || idx < 0 || idx >= seq_len) continue;
      const float4* rb = H4 + ((size_t)idx << 8);
      double acc = 0.0;
#pragma unroll
      for (int k = 0; k < 4; ++k) {
        float4 x = rb[lane + (k << 6)];
        acc += a[4*k+0] * (double)x.x + a[4*k+1] * (double)x.y
             + a[4*k+2] * (double)x.z + a[4*k+3] * (double)x.w;
      }
#pragma unroll
      for (int off = 32; off; off >>= 1) acc += __shfl_xor(acc, off);
      const double s = acc / (ncur * (sqrt(sumsq[idx]) + 1e-8));
      if (lane == jj) my_sim = s;
    }
    bool found = false; int fails = 0, p = 0, cand = 0;
    const int  myidx   = cur - HALF_WIN + lane;
    const bool myvalid = (lane < 33) && (lane != HALF_WIN) &&
                         (myidx >= 0) && (myidx < seq_len);
    for (int at = 0; at < 3; ++at) {
      uint32_t s0 = 0u, s1 = (uint32_t)at; tf2x32(ks0, ks1, s0, s1);
      double z; int bi;
      if (myvalid) {
        const uint32_t bits = tf_fold(s0, s1, 0u, (uint32_t)lane);
        const uint32_t fb   = (bits >> 9) | 0x3f800000u;
        const float    f    = __uint_as_float(fb) - 1.0f;
        const float    u    = (f > 0.0f) ? f : 1.1754943508222875e-38f;
        const double   g    = -log(-log((double)u));
        z  = g + 5.0 * my_sim;
        bi = lane;
      } else { z = -1e300; bi = 1000; }
#pragma unroll
      for (int off = 32; off; off >>= 1) {
        const double oz = __shfl_xor(z, off);
        const int    oi = __shfl_xor(bi, off);
        if (oz > z || (oz == z && oi < bi)) { z = oz; bi = oi; }
      }
      p    = bi;
      cand = cur - HALF_WIN + p;
      bool ok;
      if (plen < 2) ok = true;
      else {
        const float na = (float)sumsq[prev], nb = (float)sumsq[cur],
                    nc = (float)sumsq[cand];
        const float tr  = (na * nb * nc) /
                          ((na + 1e-8f) * (nb + 1e-8f) * (nc + 1e-8f));
        const float dev = fabsf(tr - rintf(tr));
        ok = (dev <= 0.1f) && (tr <= 1.5f);
      }
      if (ok) { found = true; break; }
      ++fails;
    }
    aborts += fails;
    if (found) {
      const double sim = __shfl(my_sim, p);
      const double nm  = fmin(min_sim, sim);
      const bool closed = (cand == start) && (plen > 2);
      prev = cur; cur = cand; plen += 1; min_sim = nm;
      if (closed) { if (nm < 0.1) detected = true; break; }
    } else {
      ++restarts;
      uint32_t h0 = 0u, h1 = 0u; tf2x32(kr0, kr1, h0, h1);
      uint32_t l0 = 0u, l1 = 1u; tf2x32(kr0, kr1, l0, l1);
      const uint32_t hi = tf_fold(h0, h1, 0u, 0u);
      const uint32_t lo = tf_fold(l0, l1, 0u, 0u);
      const uint32_t span = (uint32_t)nv;
      uint32_t mult = (65536u % span); mult = (mult * mult) % span;
      const uint32_t r = ((hi % span) * mult + (lo % span)) % span;
      const int node = viol[r];
      cur = node; prev = node; plen = 1;
    }
    key0 = nk0; key1 = nk1;
  }
  if (lane == 0) {
    if (detected)      atomicOr(&out[v], 1);
    if (aborts != 0)   atomicAdd(&out[nv], aborts);
    if (restarts != 0) atomicAdd(&out[nv + 1], restarts);
  }
}

extern "C" void kernel_launch(void* const* d_in, const int* in_sizes, int n_in,
                              void* d_out, int out_size, void* d_ws, size_t ws_size,
                              hipStream_t stream) {
  const float* H    = (const float*)d_in[0];
  const int*   viol = (const int*)d_in[1];
  const int    nv      = in_sizes[1];
  const int    seq_len = in_sizes[0] / HID;
  const int    nwalks  = nv * NUM_WALKS;

  double* sumsq = (double*)d_ws;                       // seq_len * 8 B
  double* Etab  = (double*)((char*)d_ws + (size_t)seq_len * sizeof(double));
  const size_t need2 = (size_t)seq_len * sizeof(double)
                     + (size_t)seq_len * 33 * sizeof(double);
  double* Wtab  = (double*)((char*)d_ws + need2);
  const size_t needW = need2
                     + (size_t)nwalks * WALK_LEN * 64 * sizeof(double);

  const int wblocks = (nwalks + 3) / 4;

  if (ws_size >= needW) {
    const int blocks = (seq_len + CENTERS - 1) / CENTERS;   // 512 @ 8192
    band_fused_kernel<<<blocks, 768, 0, stream>>>(H, sumsq, Etab, Wtab,
                                                  nwalks, (int*)d_out,
                                                  out_size, seq_len);
    walk_tab_kernel<<<wblocks, 256, 0, stream>>>(Etab, sumsq, Wtab, viol,
                                                 (int*)d_out, nv, seq_len);
  } else if (ws_size >= need2) {
    const int blocks = (seq_len + CENTERS - 1) / CENTERS;
    band_fused_kernel<<<blocks, 768, 0, stream>>>(H, sumsq, Etab, nullptr,
                                                  nwalks, (int*)d_out,
                                                  out_size, seq_len);
    walk_fast_kernel<<<wblocks, 256, 0, stream>>>(Etab, sumsq, viol,
                                                  (int*)d_out, nv, seq_len);
  } else {
    const int blocks = (seq_len + 3) / 4;
    rowsq_kernel<<<blocks, 256, 0, stream>>>(H, sumsq, (int*)d_out,
                                             out_size, seq_len);
    walk_ref_kernel<<<wblocks, 256, 0, stream>>>(H, viol, sumsq,
                                                 (int*)d_out, nv, seq_len);
  }
}

// Round 6
// 76.403 us; speedup vs baseline: 1.0180x; 1.0180x over previous
//
#include <hip/hip_runtime.h>
#include <stdint.h>
#include <math.h>

// ---------------------------------------------------------------------------
// SparseExplorerRouting, round 9.
//
// Carried facts (R1-R3, R5 PASSED absmax 0; R4/R6/R7 regressed; R8 split):
//   * jax_threefry_partitionable=True counter scheme; key(42) -> (0,42);
//     walk (v,w) = split child v*5+w; per-step children ctr (0,{0,1,2}).
//   * output int32 {flags[1024], sum_aborts, sum_restarts}.
//   * f64 analog math proxy for the f32 reference passes with margin
//     (~1e-13 proxy error vs ~1e-7 needed; f32 proxy NOT safe).
//   * E-table argmax(E/w) trick, w=-log(u); minE<e^0.5 == min_sim<0.1.
//   * R5 band (512thr, unrolled d-loop) ~26us: KEEPER. R5 walk 42us.
//   * R8: W-table walk = ~15-17us (KEEPER). In-band rng producer = +34us
//     REGRESSION. Calibration: f64 libm log ~950cy; fold+log ~1100cy/step.
//
// Round 9 changes:
//   * rng -> standalone rng_w_kernel (1 wave/walk, 8 steps unrolled, high
//     occupancy, not competing with the 1-block/CU band).
//   * custom fast f64 -log(u): u = k*2^-23 exactly (k = bits>>9), build
//     m in [sqrt(1/2),sqrt2) bit-exactly, atanh-form 12-term poly,
//     ~70 instrs vs libm ~950cy. Rel err ~1e-16 << 1e-7 margin. Used by
//     EVERY w producer (table, cold path, tier-2) for self-consistency.
//   * band reverted to R5 512-thread form verbatim.
// ---------------------------------------------------------------------------

#define HID        1024
#define NUM_WALKS  5
#define WALK_LEN   8
#define HALF_WIN   16
#define E_THRESH   1.6487212707001282   // exp(0.5) = exp(5 * BIRTH_DEATH_EPS)

#define CENTERS    16                   // centers per band block
#define SROWS      32                   // staged rows = CENTERS + 16 halo

__device__ __forceinline__ void tf2x32(uint32_t k0, uint32_t k1,
                                       uint32_t& x0, uint32_t& x1) {
  uint32_t ks2 = k0 ^ k1 ^ 0x1BD11BDAu;
  x0 += k0; x1 += k1;
#define TFR(r) { x0 += x1; x1 = (x1 << (r)) | (x1 >> (32 - (r))); x1 ^= x0; }
  TFR(13) TFR(15) TFR(26) TFR(6)
  x0 += k1;  x1 += ks2 + 1u;
  TFR(17) TFR(29) TFR(16) TFR(24)
  x0 += ks2; x1 += k0 + 2u;
  TFR(13) TFR(15) TFR(26) TFR(6)
  x0 += k0;  x1 += k1 + 3u;
  TFR(17) TFR(29) TFR(16) TFR(24)
  x0 += k1;  x1 += ks2 + 4u;
  TFR(13) TFR(15) TFR(26) TFR(6)
  x0 += ks2; x1 += k0 + 5u;
#undef TFR
}

__device__ __forceinline__ uint32_t tf_fold(uint32_t k0, uint32_t k1,
                                            uint32_t c0, uint32_t c1) {
  tf2x32(k0, k1, c0, c1);
  return c0 ^ c1;
}

// ---- fast f64 w = -log(u), u = k*2^-23 (k = bits>>9, 23 random bits) -------
// k==0: u clamps to 2^-126 -> w = 126*ln2. Else u = m0*2^(e-23), m0 in [1,2)
// built bit-exactly; reduce to m in [sqrt(1/2),sqrt2); log m = 2r*P(r^2),
// r=(m-1)/(m+1), |r|<=0.1716, 12 Horner terms -> rel err ~1e-16.
__device__ __forceinline__ double fast_neg_log(uint32_t bits) {
  const uint32_t k  = bits >> 9;
  const uint32_t kk = k ? k : 1u;
  const int e = 31 - __clz((int)kk);          // 0..22
  const uint64_t mant = (((uint64_t)kk) << (52 - e)) & 0x000FFFFFFFFFFFFFULL;
  double m = __longlong_as_double(0x3FF0000000000000ULL | mant);  // [1,2)
  double E = (double)(e - 23);
  const bool hi = (m >= 1.4142135623730951);
  m = hi ? m * 0.5 : m;
  E = hi ? E + 1.0 : E;
  const double r  = (m - 1.0) / (m + 1.0);
  const double r2 = r * r;
  double p =            1.0/25.0;
  p = 1.0/23.0 + r2*p;
  p = 1.0/21.0 + r2*p;
  p = 1.0/19.0 + r2*p;
  p = 1.0/17.0 + r2*p;
  p = 1.0/15.0 + r2*p;
  p = 1.0/13.0 + r2*p;
  p = 1.0/11.0 + r2*p;
  p = 1.0/9.0  + r2*p;
  p = 1.0/7.0  + r2*p;
  p = 1.0/5.0  + r2*p;
  p = 1.0/3.0  + r2*p;
  p = 1.0      + r2*p;
  const double w = -(E * 0.6931471805599453 + 2.0 * r * p);
  return k ? w : 87.33654475055310899;        // -log(2^-126)
}

// ---- rng W-table producer: one wave per walk, 8 steps unrolled -------------
__global__ __launch_bounds__(256) void rng_w_kernel(
    double* __restrict__ Wtab, int nwalks) {
  const int wv   = (int)((blockIdx.x * blockDim.x + threadIdx.x) >> 6);
  const int lane = (int)(threadIdx.x & 63);
  if (wv >= nwalks) return;
  uint32_t k0 = 0u, k1 = (uint32_t)wv;
  tf2x32(0u, 42u, k0, k1);
  k0 = __builtin_amdgcn_readfirstlane(k0);
  k1 = __builtin_amdgcn_readfirstlane(k1);
  double* row = Wtab + (((size_t)wv * WALK_LEN) << 6) + lane;
#pragma unroll
  for (int s = 0; s < WALK_LEN; ++s) {
    uint32_t nk0 = 0u, nk1 = 0u; tf2x32(k0, k1, nk0, nk1);
    uint32_t ks0 = 0u, ks1 = 1u; tf2x32(k0, k1, ks0, ks1);
    uint32_t s0  = 0u, s1  = 0u; tf2x32(ks0, ks1, s0, s1);   // attempt 0
    const uint32_t bits = tf_fold(s0, s1, 0u, (uint32_t)lane);
    row[(size_t)s << 6] = fast_neg_log(bits);
    k0 = __builtin_amdgcn_readfirstlane(nk0);
    k1 = __builtin_amdgcn_readfirstlane(nk1);
  }
}

// ---- fused band + rowsq + d_out zeroing (R5 512-thread form, verbatim) -----
__global__ __launch_bounds__(512) void band_fused_kernel(
    const float* __restrict__ H, double* __restrict__ sumsq,
    double* __restrict__ E, int* __restrict__ out, int out_n, int seq_len) {
  __shared__ __align__(16) float  tile[SROWS][HID];   // 128 KB
  __shared__ double ssq[SROWS];

  if (blockIdx.x == 0) {                 // fold d_out zeroing in (dispatch
    for (int t = threadIdx.x; t < out_n; t += 512) out[t] = 0;   // ordering
  }                                      // guarantees walk sees zeros)

  int wg = blockIdx.x;
  {
    const int nwg = gridDim.x;           // bijective XCD swizzle (nwg%8==0)
    if ((nwg & 7) == 0) wg = (wg & 7) * (nwg >> 3) + (wg >> 3);
  }
  const int wid  = (int)(threadIdx.x >> 6);   // 0..7
  const int lane = (int)(threadIdx.x & 63);
  const int i0   = wg * CENTERS;
  const float4* __restrict__ H4 = (const float4*)H;

  // ---- stage 4 rows per wave + sumsq (same order as old rowsq) ----
#pragma unroll
  for (int rr = 0; rr < 4; ++rr) {
    const int local = wid * 4 + rr;      // wave-uniform
    const int row   = i0 + local;
    if (row < seq_len) {
      const float4* src = H4 + ((size_t)row << 8);
      float4* dst = (float4*)&tile[local][0];
      double acc = 0.0;
#pragma unroll
      for (int k = 0; k < 4; ++k) {
        float4 x = src[lane + (k << 6)];
        dst[lane + (k << 6)] = x;
        acc += (double)x.x * x.x + (double)x.y * x.y
             + (double)x.z * x.z + (double)x.w * x.w;
      }
#pragma unroll
      for (int off = 32; off; off >>= 1) acc += __shfl_xor(acc, off);
      if (lane == 0) {
        ssq[local] = acc;
        if (local < CENTERS) sumsq[row] = acc;   // each row owned by 1 block
      }
    }
  }
  __syncthreads();

  // ---- 2 centers per wave, 16 forward dots each, from LDS ----
#pragma unroll
  for (int cc = 0; cc < 2; ++cc) {
    const int cl = wid * 2 + cc;         // 0..15, wave-uniform
    const int i  = i0 + cl;
    if (i >= seq_len) continue;

    double a[16];
    {
      const float4* rc = (const float4*)&tile[cl][0];
#pragma unroll
      for (int k = 0; k < 4; ++k) {
        float4 x = rc[lane + (k << 6)];
        a[4*k+0] = x.x; a[4*k+1] = x.y; a[4*k+2] = x.z; a[4*k+3] = x.w;
      }
    }
    const double ni = sqrt(ssq[cl]) + 1e-8;

    // d-loop fully unrolled: p[] indices static -> registers, no scratch.
    // Halo garbage (i+d >= seq_len) stays segregated per-d and never
    // reaches the guarded write. Bit-identical valid E.
    double p[16];
#pragma unroll
    for (int d = 0; d < 16; ++d) p[d] = 0.0;
#pragma unroll
    for (int d = 1; d <= 16; ++d) {
      const float4* rb = (const float4*)&tile[cl + d][0];
#pragma unroll
      for (int k = 0; k < 4; ++k) {
        float4 x = rb[lane + (k << 6)];
        p[d-1] += a[4*k+0] * (double)x.x + a[4*k+1] * (double)x.y
                + a[4*k+2] * (double)x.z + a[4*k+3] * (double)x.w;
      }
    }

    // multi-value reduce-scatter: value bit3..0 <- lane bit5..2
#pragma unroll
    for (int v = 0; v < 8; ++v) {                     // stage xor 32
      double send = (lane & 32) ? p[v] : p[v+8];
      double recv = __shfl_xor(send, 32);
      double mine = (lane & 32) ? p[v+8] : p[v];
      p[v] = mine + recv;
    }
#pragma unroll
    for (int v = 0; v < 4; ++v) {                     // stage xor 16
      double send = (lane & 16) ? p[v] : p[v+4];
      double recv = __shfl_xor(send, 16);
      double mine = (lane & 16) ? p[v+4] : p[v];
      p[v] = mine + recv;
    }
#pragma unroll
    for (int v = 0; v < 2; ++v) {                     // stage xor 8
      double send = (lane & 8) ? p[v] : p[v+2];
      double recv = __shfl_xor(send, 8);
      double mine = (lane & 8) ? p[v+2] : p[v];
      p[v] = mine + recv;
    }
    {                                                 // stage xor 4
      double send = (lane & 4) ? p[0] : p[1];
      double recv = __shfl_xor(send, 4);
      double mine = (lane & 4) ? p[1] : p[0];
      p[0] = mine + recv;
    }
    p[0] += __shfl_xor(p[0], 2);                      // stage xor 2
    p[0] += __shfl_xor(p[0], 1);                      // stage xor 1

    const int v = ((lane >> 2) & 1) | (((lane >> 3) & 1) << 1)
                | (((lane >> 4) & 1) << 2) | (((lane >> 5) & 1) << 3);
    const int d = v + 1;
    if ((lane & 3) == 0 && i + d < seq_len) {
      const double s  = p[0] / (ni * (sqrt(ssq[cl + d]) + 1e-8));
      const double Ev = exp(5.0 * s);
      E[(size_t)i * 33 + 16 + d]       = Ev;
      E[(size_t)(i + d) * 33 + 16 - d] = Ev;
    }
  }
}

// ---- per-row sum of squares (f64) + d_out zeroing (tier-3 only) ------------
__global__ __launch_bounds__(256) void rowsq_kernel(
    const float* __restrict__ H, double* __restrict__ sumsq,
    int* __restrict__ out, int out_n, int seq_len) {
  if (blockIdx.x == 0) {
    for (int t = threadIdx.x; t < out_n; t += 256) out[t] = 0;
  }
  const int row  = (int)((blockIdx.x * blockDim.x + threadIdx.x) >> 6);
  const int lane = threadIdx.x & 63;
  if (row >= seq_len) return;
  const float4* r = (const float4*)(H + (size_t)row * HID);
  double acc = 0.0;
#pragma unroll
  for (int k = 0; k < 4; ++k) {
    float4 x = r[lane + (k << 6)];
    acc += (double)x.x * x.x + (double)x.y * x.y
         + (double)x.z * x.z + (double)x.w * x.w;
  }
#pragma unroll
  for (int off = 32; off; off >>= 1) acc += __shfl_xor(acc, off);
  if (lane == 0) sumsq[row] = acc;
}

// ---- walk kernel, W-table variant: R5 body + attempt-0 w load --------------
__global__ __launch_bounds__(256) void walk_tab_kernel(
    const double* __restrict__ E, const double* __restrict__ sumsq,
    const double* __restrict__ Wtab, const int* __restrict__ viol,
    int* __restrict__ out, int nv, int seq_len) {
  int wave = (int)((blockIdx.x * blockDim.x + threadIdx.x) >> 6);
  const int lane = threadIdx.x & 63;
  if (wave >= nv * NUM_WALKS) return;
  wave = __builtin_amdgcn_readfirstlane(wave);
  const int v     = wave / NUM_WALKS;
  const int start = viol[v];

  uint32_t key0 = 0u, key1 = (uint32_t)wave;
  tf2x32(0u, 42u, key0, key1);
  key0 = __builtin_amdgcn_readfirstlane(key0);
  key1 = __builtin_amdgcn_readfirstlane(key1);

  int    cur = start, prev = start, plen = 1;
  double minE = 1e300;
  bool   detected = false;
  int    aborts = 0, restarts = 0;
  // carried |h|^2 of prev / cur (identical doubles to sumsq[] entries)
  double na_d = sumsq[start], nb_d = na_d;

  for (int step = 0; step < WALK_LEN; ++step) {
    // key, k_samp, k_restart = split(key,3) -- scalar (SALU) chain
    uint32_t nk0 = 0u, nk1 = 0u; tf2x32(key0, key1, nk0, nk1);
    uint32_t ks0 = 0u, ks1 = 1u; tf2x32(key0, key1, ks0, ks1);
    uint32_t kr0 = 0u, kr1 = 2u; tf2x32(key0, key1, kr0, kr1);

    const int  myidx   = cur - HALF_WIN + lane;
    const bool myvalid = (lane < 33) && (lane != HALF_WIN) &&
                         (myidx >= 0) && (myidx < seq_len);
    const int  clipped = myidx < 0 ? 0 : (myidx >= seq_len ? seq_len - 1 : myidx);
    const double Ej = E[(size_t)cur * 33 + (lane < 33 ? lane : 0)];
    const double sq_win = sumsq[clipped];   // window |h|^2, issued with Ej
    const double w0 = Wtab[(((size_t)wave * WALK_LEN + step) << 6) + lane];

    bool found = false; int fails = 0, p = 0, cand = 0;
    double nc_d = 0.0;
    for (int at = 0; at < 3; ++at) {
      double w;
      if (at == 0) {
        w = w0;                          // precomputed, identical function
      } else {                           // cold path (never taken on data)
        uint32_t s0 = 0u, s1 = (uint32_t)at; tf2x32(ks0, ks1, s0, s1);
        const uint32_t bits = tf_fold(s0, s1, 0u, (uint32_t)lane);
        w = fast_neg_log(bits);
      }
      double f; int bi;
      if (myvalid) {
        f  = Ej / w;          // argmax(E/w) == argmax(5*sim + gumbel)
        bi = lane;
      } else { f = -1.0; bi = 1000; }
#pragma unroll
      for (int off = 32; off; off >>= 1) {
        const double of = __shfl_xor(f, off);
        const int    oi = __shfl_xor(bi, off);
        if (of > f || (of == f && oi < bi)) { f = of; bi = oi; }
      }
      p    = bi;
      cand = cur - HALF_WIN + p;
      nc_d = __shfl(sq_win, p);     // == sumsq[cand], no dependent load
      bool ok;
      if (plen < 2) ok = true;
      else {
        const float na = (float)na_d, nb = (float)nb_d, nc = (float)nc_d;
        const float tr  = (na * nb * nc) /
                          ((na + 1e-8f) * (nb + 1e-8f) * (nc + 1e-8f));
        const float dev = fabsf(tr - rintf(tr));
        ok = (dev <= 0.1f) && (tr <= 1.5f);
      }
      if (ok) { found = true; break; }
      ++fails;
    }
    aborts += fails;

    if (found) {
      const double Ewin = __shfl(Ej, p);
      minE = fmin(minE, Ewin);
      const bool closed = (cand == start) && (plen > 2);
      prev = cur; cur = cand; plen += 1;
      na_d = nb_d; nb_d = nc_d;
      if (closed) { if (minE < E_THRESH) detected = true; break; }
    } else {
      ++restarts;
      uint32_t h0 = 0u, h1 = 0u; tf2x32(kr0, kr1, h0, h1);
      uint32_t l0 = 0u, l1 = 1u; tf2x32(kr0, kr1, l0, l1);
      const uint32_t hi = tf_fold(h0, h1, 0u, 0u);
      const uint32_t lo = tf_fold(l0, l1, 0u, 0u);
      const uint32_t span = (uint32_t)nv;
      uint32_t mult = (65536u % span); mult = (mult * mult) % span;
      const uint32_t r = ((hi % span) * mult + (lo % span)) % span;
      const int node = viol[r];
      cur = node; prev = node; plen = 1;
      na_d = sumsq[node]; nb_d = na_d;   // rare path, load tolerated
    }
    key0 = __builtin_amdgcn_readfirstlane(nk0);
    key1 = __builtin_amdgcn_readfirstlane(nk1);
  }

  if (lane == 0) {
    if (detected)      atomicOr(&out[v], 1);
    if (aborts != 0)   atomicAdd(&out[nv], aborts);
    if (restarts != 0) atomicAdd(&out[nv + 1], restarts);
  }
}

// ---- walk kernel: R5 body (tier-2, no W table; fast log inline) ------------
__global__ __launch_bounds__(256) void walk_fast_kernel(
    const double* __restrict__ E, const double* __restrict__ sumsq,
    const int* __restrict__ viol, int* __restrict__ out,
    int nv, int seq_len) {
  int wave = (int)((blockIdx.x * blockDim.x + threadIdx.x) >> 6);
  const int lane = threadIdx.x & 63;
  if (wave >= nv * NUM_WALKS) return;
  wave = __builtin_amdgcn_readfirstlane(wave);
  const int v     = wave / NUM_WALKS;
  const int start = viol[v];

  uint32_t key0 = 0u, key1 = (uint32_t)wave;
  tf2x32(0u, 42u, key0, key1);
  key0 = __builtin_amdgcn_readfirstlane(key0);
  key1 = __builtin_amdgcn_readfirstlane(key1);

  int    cur = start, prev = start, plen = 1;
  double minE = 1e300;
  bool   detected = false;
  int    aborts = 0, restarts = 0;
  double na_d = sumsq[start], nb_d = na_d;

  for (int step = 0; step < WALK_LEN; ++step) {
    uint32_t nk0 = 0u, nk1 = 0u; tf2x32(key0, key1, nk0, nk1);
    uint32_t ks0 = 0u, ks1 = 1u; tf2x32(key0, key1, ks0, ks1);
    uint32_t kr0 = 0u, kr1 = 2u; tf2x32(key0, key1, kr0, kr1);

    const int  myidx   = cur - HALF_WIN + lane;
    const bool myvalid = (lane < 33) && (lane != HALF_WIN) &&
                         (myidx >= 0) && (myidx < seq_len);
    const int  clipped = myidx < 0 ? 0 : (myidx >= seq_len ? seq_len - 1 : myidx);
    const double Ej = E[(size_t)cur * 33 + (lane < 33 ? lane : 0)];
    const double sq_win = sumsq[clipped];

    bool found = false; int fails = 0, p = 0, cand = 0;
    double nc_d = 0.0;
    for (int at = 0; at < 3; ++at) {
      uint32_t s0 = 0u, s1 = (uint32_t)at; tf2x32(ks0, ks1, s0, s1);
      double f; int bi;
      if (myvalid) {
        const uint32_t bits = tf_fold(s0, s1, 0u, (uint32_t)lane);
        const double   w    = fast_neg_log(bits);
        f  = Ej / w;
        bi = lane;
      } else { f = -1.0; bi = 1000; }
#pragma unroll
      for (int off = 32; off; off >>= 1) {
        const double of = __shfl_xor(f, off);
        const int    oi = __shfl_xor(bi, off);
        if (of > f || (of == f && oi < bi)) { f = of; bi = oi; }
      }
      p    = bi;
      cand = cur - HALF_WIN + p;
      nc_d = __shfl(sq_win, p);
      bool ok;
      if (plen < 2) ok = true;
      else {
        const float na = (float)na_d, nb = (float)nb_d, nc = (float)nc_d;
        const float tr  = (na * nb * nc) /
                          ((na + 1e-8f) * (nb + 1e-8f) * (nc + 1e-8f));
        const float dev = fabsf(tr - rintf(tr));
        ok = (dev <= 0.1f) && (tr <= 1.5f);
      }
      if (ok) { found = true; break; }
      ++fails;
    }
    aborts += fails;

    if (found) {
      const double Ewin = __shfl(Ej, p);
      minE = fmin(minE, Ewin);
      const bool closed = (cand == start) && (plen > 2);
      prev = cur; cur = cand; plen += 1;
      na_d = nb_d; nb_d = nc_d;
      if (closed) { if (minE < E_THRESH) detected = true; break; }
    } else {
      ++restarts;
      uint32_t h0 = 0u, h1 = 0u; tf2x32(kr0, kr1, h0, h1);
      uint32_t l0 = 0u, l1 = 1u; tf2x32(kr0, kr1, l0, l1);
      const uint32_t hi = tf_fold(h0, h1, 0u, 0u);
      const uint32_t lo = tf_fold(l0, l1, 0u, 0u);
      const uint32_t span = (uint32_t)nv;
      uint32_t mult = (65536u % span); mult = (mult * mult) % span;
      const uint32_t r = ((hi % span) * mult + (lo % span)) % span;
      const int node = viol[r];
      cur = node; prev = node; plen = 1;
      na_d = sumsq[node]; nb_d = na_d;
    }
    key0 = __builtin_amdgcn_readfirstlane(nk0);
    key1 = __builtin_amdgcn_readfirstlane(nk1);
  }

  if (lane == 0) {
    if (detected)      atomicOr(&out[v], 1);
    if (aborts != 0)   atomicAdd(&out[nv], aborts);
    if (restarts != 0) atomicAdd(&out[nv + 1], restarts);
  }
}

// ---- fallback: round-1 in-walk dot kernel (only if ws too small) -----------
__global__ __launch_bounds__(256) void walk_ref_kernel(
    const float* __restrict__ H, const int* __restrict__ viol,
    const double* __restrict__ sumsq, int* __restrict__ out,
    int nv, int seq_len) {
  const int wave = (int)((blockIdx.x * blockDim.x + threadIdx.x) >> 6);
  const int lane = threadIdx.x & 63;
  if (wave >= nv * NUM_WALKS) return;
  const int v     = wave / NUM_WALKS;
  const int start = viol[v];
  uint32_t key0 = 0u, key1 = (uint32_t)wave;
  tf2x32(0u, 42u, key0, key1);
  const float4* __restrict__ H4 = (const float4*)H;
  int    cur = start, prev = start, plen = 1;
  double min_sim = 1e9;
  bool   detected = false;
  int    aborts = 0, restarts = 0;
  for (int step = 0; step < WALK_LEN; ++step) {
    uint32_t nk0 = 0u, nk1 = 0u; tf2x32(key0, key1, nk0, nk1);
    uint32_t ks0 = 0u, ks1 = 1u; tf2x32(key0, key1, ks0, ks1);
    uint32_t kr0 = 0u, kr1 = 2u; tf2x32(key0, key1, kr0, kr1);
    const double ncur = sqrt(sumsq[cur]) + 1e-8;
    double a[16];
    {
      const float4* rc = H4 + ((size_t)cur << 8);
#pragma unroll
      for (int k = 0; k < 4; ++k) {
        float4 x = rc[lane + (k << 6)];
        a[4*k+0] = x.x; a[4*k+1] = x.y; a[4*k+2] = x.z; a[4*k+3] = x.w;
      }
    }
    double my_sim = 0.0;
    for (int jj = 0; jj < 33; ++jj) {
      const int idx = cur - HALF_WIN + jj;
      if (jj == HALF_WIN || idx < 0 || idx >= seq_len) continue;
      const float4* rb = H4 + ((size_t)idx << 8);
      double acc = 0.0;
#pragma unroll
      for (int k = 0; k < 4; ++k) {
        float4 x = rb[lane + (k << 6)];
        acc += a[4*k+0] * (double)x.x + a[4*k+1] * (double)x.y
             + a[4*k+2] * (double)x.z + a[4*k+3] * (double)x.w;
      }
#pragma unroll
      for (int off = 32; off; off >>= 1) acc += __shfl_xor(acc, off);
      const double s = acc / (ncur * (sqrt(sumsq[idx]) + 1e-8));
      if (lane == jj) my_sim = s;
    }
    bool found = false; int fails = 0, p = 0, cand = 0;
    const int  myidx   = cur - HALF_WIN + lane;
    const bool myvalid = (lane < 33) && (lane != HALF_WIN) &&
                         (myidx >= 0) && (myidx < seq_len);
    for (int at = 0; at < 3; ++at) {
      uint32_t s0 = 0u, s1 = (uint32_t)at; tf2x32(ks0, ks1, s0, s1);
      double z; int bi;
      if (myvalid) {
        const uint32_t bits = tf_fold(s0, s1, 0u, (uint32_t)lane);
        const uint32_t fb   = (bits >> 9) | 0x3f800000u;
        const float    f    = __uint_as_float(fb) - 1.0f;
        const float    u    = (f > 0.0f) ? f : 1.1754943508222875e-38f;
        const double   g    = -log(-log((double)u));
        z  = g + 5.0 * my_sim;
        bi = lane;
      } else { z = -1e300; bi = 1000; }
#pragma unroll
      for (int off = 32; off; off >>= 1) {
        const double oz = __shfl_xor(z, off);
        const int    oi = __shfl_xor(bi, off);
        if (oz > z || (oz == z && oi < bi)) { z = oz; bi = oi; }
      }
      p    = bi;
      cand = cur - HALF_WIN + p;
      bool ok;
      if (plen < 2) ok = true;
      else {
        const float na = (float)sumsq[prev], nb = (float)sumsq[cur],
                    nc = (float)sumsq[cand];
        const float tr  = (na * nb * nc) /
                          ((na + 1e-8f) * (nb + 1e-8f) * (nc + 1e-8f));
        const float dev = fabsf(tr - rintf(tr));
        ok = (dev <= 0.1f) && (tr <= 1.5f);
      }
      if (ok) { found = true; break; }
      ++fails;
    }
    aborts += fails;
    if (found) {
      const double sim = __shfl(my_sim, p);
      const double nm  = fmin(min_sim, sim);
      const bool closed = (cand == start) && (plen > 2);
      prev = cur; cur = cand; plen += 1; min_sim = nm;
      if (closed) { if (nm < 0.1) detected = true; break; }
    } else {
      ++restarts;
      uint32_t h0 = 0u, h1 = 0u; tf2x32(kr0, kr1, h0, h1);
      uint32_t l0 = 0u, l1 = 1u; tf2x32(kr0, kr1, l0, l1);
      const uint32_t hi = tf_fold(h0, h1, 0u, 0u);
      const uint32_t lo = tf_fold(l0, l1, 0u, 0u);
      const uint32_t span = (uint32_t)nv;
      uint32_t mult = (65536u % span); mult = (mult * mult) % span;
      const uint32_t r = ((hi % span) * mult + (lo % span)) % span;
      const int node = viol[r];
      cur = node; prev = node; plen = 1;
    }
    key0 = nk0; key1 = nk1;
  }
  if (lane == 0) {
    if (detected)      atomicOr(&out[v], 1);
    if (aborts != 0)   atomicAdd(&out[nv], aborts);
    if (restarts != 0) atomicAdd(&out[nv + 1], restarts);
  }
}

extern "C" void kernel_launch(void* const* d_in, const int* in_sizes, int n_in,
                              void* d_out, int out_size, void* d_ws, size_t ws_size,
                              hipStream_t stream) {
  const float* H    = (const float*)d_in[0];
  const int*   viol = (const int*)d_in[1];
  const int    nv      = in_sizes[1];
  const int    seq_len = in_sizes[0] / HID;
  const int    nwalks  = nv * NUM_WALKS;

  double* sumsq = (double*)d_ws;                       // seq_len * 8 B
  double* Etab  = (double*)((char*)d_ws + (size_t)seq_len * sizeof(double));
  const size_t need2 = (size_t)seq_len * sizeof(double)
                     + (size_t)seq_len * 33 * sizeof(double);
  double* Wtab  = (double*)((char*)d_ws + need2);
  const size_t needW = need2
                     + (size_t)nwalks * WALK_LEN * 64 * sizeof(double);

  const int wblocks = (nwalks + 3) / 4;

  if (ws_size >= needW) {
    rng_w_kernel<<<wblocks, 256, 0, stream>>>(Wtab, nwalks);
    const int blocks = (seq_len + CENTERS - 1) / CENTERS;   // 512 @ 8192
    band_fused_kernel<<<blocks, 512, 0, stream>>>(H, sumsq, Etab,
                                                  (int*)d_out, out_size,
                                                  seq_len);
    walk_tab_kernel<<<wblocks, 256, 0, stream>>>(Etab, sumsq, Wtab, viol,
                                                 (int*)d_out, nv, seq_len);
  } else if (ws_size >= need2) {
    const int blocks = (seq_len + CENTERS - 1) / CENTERS;
    band_fused_kernel<<<blocks, 512, 0, stream>>>(H, sumsq, Etab,
                                                  (int*)d_out, out_size,
                                                  seq_len);
    walk_fast_kernel<<<wblocks, 256, 0, stream>>>(Etab, sumsq, viol,
                                                  (int*)d_out, nv, seq_len);
  } else {
    const int blocks = (seq_len + 3) / 4;
    rowsq_kernel<<<blocks, 256, 0, stream>>>(H, sumsq, (int*)d_out,
                                             out_size, seq_len);
    walk_ref_kernel<<<wblocks, 256, 0, stream>>>(H, viol, sumsq,
                                                 (int*)d_out, nv, seq_len);
  }
}

// Round 7
// 75.968 us; speedup vs baseline: 1.0238x; 1.0057x over previous
//
#include <hip/hip_runtime.h>
#include <stdint.h>
#include <math.h>

// ---------------------------------------------------------------------------
// SparseExplorerRouting, round 10.
//
// Carried facts (R1-R3, R5 PASSED absmax 0; R4/R6/R7 regressed; R8/R9 mixed):
//   * jax_threefry_partitionable=True counter scheme; key(42) -> (0,42);
//     walk (v,w) = split child v*5+w; per-step children ctr (0,{0,1,2}).
//   * output int32 {flags[1024], sum_aborts, sum_restarts}.
//   * f64 analog proxy passes with ~1e-7 margin headroom (proxy-vs-f32-ref
//     discrepancy ~1e-13 tolerated) -> 1e-16 f64 reorderings are free.
//   * E-table argmax(E/w) trick, w=-log(u); minE<e^0.5 == min_sim<0.1.
//   * Walk restructures lose (R4/R6); R5 walk body is the schedule.
//   * W-table walk = ~17us (KEEPER). Producing 41k wave-values of w costs
//     25-33us wherever computed (R8 in-band libm 34, R9 standalone fastlog
//     33, inline-in-walk libm 25). fast_neg_log ~= libm in practice.
//   * Band at 131KB LDS = 1 block/CU = 2 waves/SIMD; that occupancy is its
//     limiter (26us vs ~8us issue model at 4 waves/SIMD).
//
// Round 10 changes:
//   * rng pair-packed: 2 walks per rng wave (32 useful slots each), halving
//     fold+log wave-steps; Wtab rows of 32 (slot = j-(j>16)), 10.5 MB.
//   * band K-split staging: tile[32][512] f32 = 64KB -> 2 blocks/CU.
//     stage half0 / compute / stage half1 / compute; per-lane accumulation
//     order preserved; owner-lane sums the two halves' reduce-scatter
//     outputs (1e-16-level reorder only).
// ---------------------------------------------------------------------------

#define HID        1024
#define NUM_WALKS  5
#define WALK_LEN   8
#define HALF_WIN   16
#define E_THRESH   1.6487212707001282   // exp(0.5) = exp(5 * BIRTH_DEATH_EPS)

#define CENTERS    16                   // centers per band block
#define SROWS      32                   // staged rows = CENTERS + 16 halo
#define KHALF      512                  // staged columns per pass

__device__ __forceinline__ void tf2x32(uint32_t k0, uint32_t k1,
                                       uint32_t& x0, uint32_t& x1) {
  uint32_t ks2 = k0 ^ k1 ^ 0x1BD11BDAu;
  x0 += k0; x1 += k1;
#define TFR(r) { x0 += x1; x1 = (x1 << (r)) | (x1 >> (32 - (r))); x1 ^= x0; }
  TFR(13) TFR(15) TFR(26) TFR(6)
  x0 += k1;  x1 += ks2 + 1u;
  TFR(17) TFR(29) TFR(16) TFR(24)
  x0 += ks2; x1 += k0 + 2u;
  TFR(13) TFR(15) TFR(26) TFR(6)
  x0 += k0;  x1 += k1 + 3u;
  TFR(17) TFR(29) TFR(16) TFR(24)
  x0 += k1;  x1 += ks2 + 4u;
  TFR(13) TFR(15) TFR(26) TFR(6)
  x0 += ks2; x1 += k0 + 5u;
#undef TFR
}

__device__ __forceinline__ uint32_t tf_fold(uint32_t k0, uint32_t k1,
                                            uint32_t c0, uint32_t c1) {
  tf2x32(k0, k1, c0, c1);
  return c0 ^ c1;
}

// fast f64 w = -log(u), u = k*2^-23 (k = bits>>9). Proven passing in R9.
__device__ __forceinline__ double fast_neg_log(uint32_t bits) {
  const uint32_t k  = bits >> 9;
  const uint32_t kk = k ? k : 1u;
  const int e = 31 - __clz((int)kk);          // 0..22
  const uint64_t mant = (((uint64_t)kk) << (52 - e)) & 0x000FFFFFFFFFFFFFULL;
  double m = __longlong_as_double(0x3FF0000000000000ULL | mant);  // [1,2)
  double E = (double)(e - 23);
  const bool hi = (m >= 1.4142135623730951);
  m = hi ? m * 0.5 : m;
  E = hi ? E + 1.0 : E;
  const double r  = (m - 1.0) / (m + 1.0);
  const double r2 = r * r;
  double p =            1.0/25.0;
  p = 1.0/23.0 + r2*p;
  p = 1.0/21.0 + r2*p;
  p = 1.0/19.0 + r2*p;
  p = 1.0/17.0 + r2*p;
  p = 1.0/15.0 + r2*p;
  p = 1.0/13.0 + r2*p;
  p = 1.0/11.0 + r2*p;
  p = 1.0/9.0  + r2*p;
  p = 1.0/7.0  + r2*p;
  p = 1.0/5.0  + r2*p;
  p = 1.0/3.0  + r2*p;
  p = 1.0      + r2*p;
  const double w = -(E * 0.6931471805599453 + 2.0 * r * p);
  return k ? w : 87.33654475055310899;        // -log(2^-126)
}

// ---- rng W-table producer, PAIR-PACKED: 2 walks per wave -------------------
// Lanes 0..31 serve walk A, 32..63 walk B; slot sl -> candidate j = sl+(sl>15)
// (skips j=16 == cur). W rows are 32 doubles. Values identical to inline.
__global__ __launch_bounds__(256) void rng_w_kernel(
    double* __restrict__ Wtab, int nwalks) {
  int W = (int)((blockIdx.x * blockDim.x + threadIdx.x) >> 6);  // pair id
  const int lane = (int)(threadIdx.x & 63);
  if (W * 2 >= nwalks) return;
  W = __builtin_amdgcn_readfirstlane(W);
  const int  wA   = W * 2, wB = W * 2 + 1;
  const bool hasB = (wB < nwalks);
  const int  l5   = lane >> 5;               // 0 = A, 1 = B
  const int  sl   = lane & 31;               // slot
  const uint32_t j = (uint32_t)(sl + (sl > 15 ? 1 : 0));

  uint32_t kA0 = 0u, kA1 = (uint32_t)wA; tf2x32(0u, 42u, kA0, kA1);
  uint32_t kB0 = 0u, kB1 = (uint32_t)(hasB ? wB : wA); tf2x32(0u, 42u, kB0, kB1);
  kA0 = __builtin_amdgcn_readfirstlane(kA0);
  kA1 = __builtin_amdgcn_readfirstlane(kA1);
  kB0 = __builtin_amdgcn_readfirstlane(kB0);
  kB1 = __builtin_amdgcn_readfirstlane(kB1);

  const size_t baseA = ((size_t)wA * WALK_LEN) << 5;
  const size_t baseB = ((size_t)wB * WALK_LEN) << 5;

#pragma unroll
  for (int s = 0; s < WALK_LEN; ++s) {
    // SALU: next-key + sample-key chains for both walks; attempt-0 bits key
    uint32_t nkA0 = 0u, nkA1 = 0u; tf2x32(kA0, kA1, nkA0, nkA1);
    uint32_t ksA0 = 0u, ksA1 = 1u; tf2x32(kA0, kA1, ksA0, ksA1);
    uint32_t sA0  = 0u, sA1  = 0u; tf2x32(ksA0, ksA1, sA0, sA1);   // at=0
    uint32_t nkB0 = 0u, nkB1 = 0u; tf2x32(kB0, kB1, nkB0, nkB1);
    uint32_t ksB0 = 0u, ksB1 = 1u; tf2x32(kB0, kB1, ksB0, ksB1);
    uint32_t sB0  = 0u, sB1  = 0u; tf2x32(ksB0, ksB1, sB0, sB1);   // at=0
    const uint32_t s0 = l5 ? sB0 : sA0;     // 2-op per-lane select
    const uint32_t s1 = l5 ? sB1 : sA1;
    const uint32_t bits = tf_fold(s0, s1, 0u, j);
    const double   w    = fast_neg_log(bits);
    if (!l5) {
      Wtab[baseA + ((size_t)s << 5) + sl] = w;
    } else if (hasB) {
      Wtab[baseB + ((size_t)s << 5) + sl] = w;
    }
    kA0 = __builtin_amdgcn_readfirstlane(nkA0);
    kA1 = __builtin_amdgcn_readfirstlane(nkA1);
    kB0 = __builtin_amdgcn_readfirstlane(nkB0);
    kB1 = __builtin_amdgcn_readfirstlane(nkB1);
  }
}

// ---- fused band + rowsq + d_out zeroing, K-SPLIT staging (64 KB LDS) -------
__global__ __launch_bounds__(512) void band_fused_kernel(
    const float* __restrict__ H, double* __restrict__ sumsq,
    double* __restrict__ E, int* __restrict__ out, int out_n, int seq_len) {
  __shared__ __align__(16) float  tile[SROWS][KHALF];   // 64 KB
  __shared__ double ssq[SROWS];

  if (blockIdx.x == 0) {                 // fold d_out zeroing in (dispatch
    for (int t = threadIdx.x; t < out_n; t += 512) out[t] = 0;   // ordering
  }                                      // guarantees walk sees zeros)

  int wg = blockIdx.x;
  {
    const int nwg = gridDim.x;           // bijective XCD swizzle (nwg%8==0)
    if ((nwg & 7) == 0) wg = (wg & 7) * (nwg >> 3) + (wg >> 3);
  }
  const int wid  = (int)(threadIdx.x >> 6);   // 0..7
  const int lane = (int)(threadIdx.x & 63);
  const int i0   = wg * CENTERS;
  const float4* __restrict__ H4 = (const float4*)H;

  double acc[4]  = {0.0, 0.0, 0.0, 0.0};   // per staged row, across halves
  double dsum[2] = {0.0, 0.0};             // per-cc owner-lane band sums

#pragma unroll
  for (int half = 0; half < 2; ++half) {
    // ---- stage 4 rows per wave, cols [half*512, half*512+512) ----
#pragma unroll
    for (int rr = 0; rr < 4; ++rr) {
      const int local = wid * 4 + rr;    // wave-uniform
      const int row   = i0 + local;
      if (row < seq_len) {
        const float4* src = H4 + ((size_t)row << 8);
        float4* dst = (float4*)&tile[local][0];
#pragma unroll
        for (int kk = 0; kk < 2; ++kk) { // global chunk k = 2*half + kk
          float4 x = src[lane + ((half * 2 + kk) << 6)];
          dst[lane + (kk << 6)] = x;
          acc[rr] += (double)x.x * x.x + (double)x.y * x.y
                   + (double)x.z * x.z + (double)x.w * x.w;
        }
      }
    }
    if (half == 1) {                     // finalize sumsq (same per-lane
#pragma unroll                           //  order k0..k3, one butterfly)
      for (int rr = 0; rr < 4; ++rr) {
        const int local = wid * 4 + rr;
        const int row   = i0 + local;
        if (row < seq_len) {
          double a = acc[rr];
#pragma unroll
          for (int off = 32; off; off >>= 1) a += __shfl_xor(a, off);
          if (lane == 0) {
            ssq[local] = a;
            if (local < CENTERS) sumsq[row] = a;  // row owned by 1 block
          }
        }
      }
    }
    __syncthreads();

    // ---- 2 centers per wave, 16 partial dots each, from LDS half ----
#pragma unroll
    for (int cc = 0; cc < 2; ++cc) {
      const int cl = wid * 2 + cc;       // 0..15, wave-uniform
      const int i  = i0 + cl;
      if (i >= seq_len) continue;

      double a[8];
      {
        const float4* rc = (const float4*)&tile[cl][0];
#pragma unroll
        for (int kk = 0; kk < 2; ++kk) {
          float4 x = rc[lane + (kk << 6)];
          a[4*kk+0] = x.x; a[4*kk+1] = x.y; a[4*kk+2] = x.z; a[4*kk+3] = x.w;
        }
      }

      double p[16];
#pragma unroll
      for (int d = 0; d < 16; ++d) p[d] = 0.0;
#pragma unroll
      for (int d = 1; d <= 16; ++d) {
        const float4* rb = (const float4*)&tile[cl + d][0];
#pragma unroll
        for (int kk = 0; kk < 2; ++kk) {
          float4 x = rb[lane + (kk << 6)];
          p[d-1] += a[4*kk+0] * (double)x.x + a[4*kk+1] * (double)x.y
                  + a[4*kk+2] * (double)x.z + a[4*kk+3] * (double)x.w;
        }
      }

      // multi-value reduce-scatter: value bit3..0 <- lane bit5..2
#pragma unroll
      for (int v = 0; v < 8; ++v) {                     // stage xor 32
        double send = (lane & 32) ? p[v] : p[v+8];
        double recv = __shfl_xor(send, 32);
        double mine = (lane & 32) ? p[v+8] : p[v];
        p[v] = mine + recv;
      }
#pragma unroll
      for (int v = 0; v < 4; ++v) {                     // stage xor 16
        double send = (lane & 16) ? p[v] : p[v+4];
        double recv = __shfl_xor(send, 16);
        double mine = (lane & 16) ? p[v+4] : p[v];
        p[v] = mine + recv;
      }
#pragma unroll
      for (int v = 0; v < 2; ++v) {                     // stage xor 8
        double send = (lane & 8) ? p[v] : p[v+2];
        double recv = __shfl_xor(send, 8);
        double mine = (lane & 8) ? p[v+2] : p[v];
        p[v] = mine + recv;
      }
      {                                                 // stage xor 4
        double send = (lane & 4) ? p[0] : p[1];
        double recv = __shfl_xor(send, 4);
        double mine = (lane & 4) ? p[1] : p[0];
        p[0] = mine + recv;
      }
      p[0] += __shfl_xor(p[0], 2);                      // stage xor 2
      p[0] += __shfl_xor(p[0], 1);                      // stage xor 1

      dsum[cc] += p[0];                  // owner-lane: half-sum accumulate
    }
    __syncthreads();                     // compute done before re-stage
  }

  // ---- epilogue: lane owns d = v+1 for its cc centers ----
  const int v = ((lane >> 2) & 1) | (((lane >> 3) & 1) << 1)
              | (((lane >> 4) & 1) << 2) | (((lane >> 5) & 1) << 3);
  const int d = v + 1;
#pragma unroll
  for (int cc = 0; cc < 2; ++cc) {
    const int cl = wid * 2 + cc;
    const int i  = i0 + cl;
    if (i < seq_len && (lane & 3) == 0 && i + d < seq_len) {
      const double ni = sqrt(ssq[cl]) + 1e-8;
      const double s  = dsum[cc] / (ni * (sqrt(ssq[cl + d]) + 1e-8));
      const double Ev = exp(5.0 * s);
      E[(size_t)i * 33 + 16 + d]       = Ev;
      E[(size_t)(i + d) * 33 + 16 - d] = Ev;
    }
  }
}

// ---- per-row sum of squares (f64) + d_out zeroing (tier-3 only) ------------
__global__ __launch_bounds__(256) void rowsq_kernel(
    const float* __restrict__ H, double* __restrict__ sumsq,
    int* __restrict__ out, int out_n, int seq_len) {
  if (blockIdx.x == 0) {
    for (int t = threadIdx.x; t < out_n; t += 256) out[t] = 0;
  }
  const int row  = (int)((blockIdx.x * blockDim.x + threadIdx.x) >> 6);
  const int lane = threadIdx.x & 63;
  if (row >= seq_len) return;
  const float4* r = (const float4*)(H + (size_t)row * HID);
  double acc = 0.0;
#pragma unroll
  for (int k = 0; k < 4; ++k) {
    float4 x = r[lane + (k << 6)];
    acc += (double)x.x * x.x + (double)x.y * x.y
         + (double)x.z * x.z + (double)x.w * x.w;
  }
#pragma unroll
  for (int off = 32; off; off >>= 1) acc += __shfl_xor(acc, off);
  if (lane == 0) sumsq[row] = acc;
}

// ---- walk kernel, W-table variant: R5 body + attempt-0 w load (32-slot) ----
__global__ __launch_bounds__(256) void walk_tab_kernel(
    const double* __restrict__ E, const double* __restrict__ sumsq,
    const double* __restrict__ Wtab, const int* __restrict__ viol,
    int* __restrict__ out, int nv, int seq_len) {
  int wave = (int)((blockIdx.x * blockDim.x + threadIdx.x) >> 6);
  const int lane = threadIdx.x & 63;
  if (wave >= nv * NUM_WALKS) return;
  wave = __builtin_amdgcn_readfirstlane(wave);
  const int v     = wave / NUM_WALKS;
  const int start = viol[v];
  // my W slot (valid lanes only; others read slot 0 harmlessly)
  const int slot  = (lane < 33 && lane != HALF_WIN) ? (lane - (lane > HALF_WIN))
                                                    : 0;

  uint32_t key0 = 0u, key1 = (uint32_t)wave;
  tf2x32(0u, 42u, key0, key1);
  key0 = __builtin_amdgcn_readfirstlane(key0);
  key1 = __builtin_amdgcn_readfirstlane(key1);

  int    cur = start, prev = start, plen = 1;
  double minE = 1e300;
  bool   detected = false;
  int    aborts = 0, restarts = 0;
  // carried |h|^2 of prev / cur (identical doubles to sumsq[] entries)
  double na_d = sumsq[start], nb_d = na_d;

  for (int step = 0; step < WALK_LEN; ++step) {
    // key, k_samp, k_restart = split(key,3) -- scalar (SALU) chain
    uint32_t nk0 = 0u, nk1 = 0u; tf2x32(key0, key1, nk0, nk1);
    uint32_t ks0 = 0u, ks1 = 1u; tf2x32(key0, key1, ks0, ks1);
    uint32_t kr0 = 0u, kr1 = 2u; tf2x32(key0, key1, kr0, kr1);

    const int  myidx   = cur - HALF_WIN + lane;
    const bool myvalid = (lane < 33) && (lane != HALF_WIN) &&
                         (myidx >= 0) && (myidx < seq_len);
    const int  clipped = myidx < 0 ? 0 : (myidx >= seq_len ? seq_len - 1 : myidx);
    const double Ej = E[(size_t)cur * 33 + (lane < 33 ? lane : 0)];
    const double sq_win = sumsq[clipped];   // window |h|^2, issued with Ej
    const double w0 = Wtab[(((size_t)wave * WALK_LEN + step) << 5) + slot];

    bool found = false; int fails = 0, p = 0, cand = 0;
    double nc_d = 0.0;
    for (int at = 0; at < 3; ++at) {
      double w;
      if (at == 0) {
        w = w0;                          // precomputed, identical function
      } else {                           // cold path (rare)
        uint32_t s0 = 0u, s1 = (uint32_t)at; tf2x32(ks0, ks1, s0, s1);
        const uint32_t bits = tf_fold(s0, s1, 0u, (uint32_t)lane);
        w = fast_neg_log(bits);
      }
      double f; int bi;
      if (myvalid) {
        f  = Ej / w;          // argmax(E/w) == argmax(5*sim + gumbel)
        bi = lane;
      } else { f = -1.0; bi = 1000; }
#pragma unroll
      for (int off = 32; off; off >>= 1) {
        const double of = __shfl_xor(f, off);
        const int    oi = __shfl_xor(bi, off);
        if (of > f || (of == f && oi < bi)) { f = of; bi = oi; }
      }
      p    = bi;
      cand = cur - HALF_WIN + p;
      nc_d = __shfl(sq_win, p);     // == sumsq[cand], no dependent load
      bool ok;
      if (plen < 2) ok = true;
      else {
        const float na = (float)na_d, nb = (float)nb_d, nc = (float)nc_d;
        const float tr  = (na * nb * nc) /
                          ((na + 1e-8f) * (nb + 1e-8f) * (nc + 1e-8f));
        const float dev = fabsf(tr - rintf(tr));
        ok = (dev <= 0.1f) && (tr <= 1.5f);
      }
      if (ok) { found = true; break; }
      ++fails;
    }
    aborts += fails;

    if (found) {
      const double Ewin = __shfl(Ej, p);
      minE = fmin(minE, Ewin);
      const bool closed = (cand == start) && (plen > 2);
      prev = cur; cur = cand; plen += 1;
      na_d = nb_d; nb_d = nc_d;
      if (closed) { if (minE < E_THRESH) detected = true; break; }
    } else {
      ++restarts;
      uint32_t h0 = 0u, h1 = 0u; tf2x32(kr0, kr1, h0, h1);
      uint32_t l0 = 0u, l1 = 1u; tf2x32(kr0, kr1, l0, l1);
      const uint32_t hi = tf_fold(h0, h1, 0u, 0u);
      const uint32_t lo = tf_fold(l0, l1, 0u, 0u);
      const uint32_t span = (uint32_t)nv;
      uint32_t mult = (65536u % span); mult = (mult * mult) % span;
      const uint32_t r = ((hi % span) * mult + (lo % span)) % span;
      const int node = viol[r];
      cur = node; prev = node; plen = 1;
      na_d = sumsq[node]; nb_d = na_d;   // rare path, load tolerated
    }
    key0 = __builtin_amdgcn_readfirstlane(nk0);
    key1 = __builtin_amdgcn_readfirstlane(nk1);
  }

  if (lane == 0) {
    if (detected)      atomicOr(&out[v], 1);
    if (aborts != 0)   atomicAdd(&out[nv], aborts);
    if (restarts != 0) atomicAdd(&out[nv + 1], restarts);
  }
}

// ---- walk kernel: R5 body (tier-2, no W table; fast log inline) ------------
__global__ __launch_bounds__(256) void walk_fast_kernel(
    const double* __restrict__ E, const double* __restrict__ sumsq,
    const int* __restrict__ viol, int* __restrict__ out,
    int nv, int seq_len) {
  int wave = (int)((blockIdx.x * blockDim.x + threadIdx.x) >> 6);
  const int lane = threadIdx.x & 63;
  if (wave >= nv * NUM_WALKS) return;
  wave = __builtin_amdgcn_readfirstlane(wave);
  const int v     = wave / NUM_WALKS;
  const int start = viol[v];

  uint32_t key0 = 0u, key1 = (uint32_t)wave;
  tf2x32(0u, 42u, key0, key1);
  key0 = __builtin_amdgcn_readfirstlane(key0);
  key1 = __builtin_amdgcn_readfirstlane(key1);

  int    cur = start, prev = start, plen = 1;
  double minE = 1e300;
  bool   detected = false;
  int    aborts = 0, restarts = 0;
  double na_d = sumsq[start], nb_d = na_d;

  for (int step = 0; step < WALK_LEN; ++step) {
    uint32_t nk0 = 0u, nk1 = 0u; tf2x32(key0, key1, nk0, nk1);
    uint32_t ks0 = 0u, ks1 = 1u; tf2x32(key0, key1, ks0, ks1);
    uint32_t kr0 = 0u, kr1 = 2u; tf2x32(key0, key1, kr0, kr1);

    const int  myidx   = cur - HALF_WIN + lane;
    const bool myvalid = (lane < 33) && (lane != HALF_WIN) &&
                         (myidx >= 0) && (myidx < seq_len);
    const int  clipped = myidx < 0 ? 0 : (myidx >= seq_len ? seq_len - 1 : myidx);
    const double Ej = E[(size_t)cur * 33 + (lane < 33 ? lane : 0)];
    const double sq_win = sumsq[clipped];

    bool found = false; int fails = 0, p = 0, cand = 0;
    double nc_d = 0.0;
    for (int at = 0; at < 3; ++at) {
      uint32_t s0 = 0u, s1 = (uint32_t)at; tf2x32(ks0, ks1, s0, s1);
      double f; int bi;
      if (myvalid) {
        const uint32_t bits = tf_fold(s0, s1, 0u, (uint32_t)lane);
        const double   w    = fast_neg_log(bits);
        f  = Ej / w;
        bi = lane;
      } else { f = -1.0; bi = 1000; }
#pragma unroll
      for (int off = 32; off; off >>= 1) {
        const double of = __shfl_xor(f, off);
        const int    oi = __shfl_xor(bi, off);
        if (of > f || (of == f && oi < bi)) { f = of; bi = oi; }
      }
      p    = bi;
      cand = cur - HALF_WIN + p;
      nc_d = __shfl(sq_win, p);
      bool ok;
      if (plen < 2) ok = true;
      else {
        const float na = (float)na_d, nb = (float)nb_d, nc = (float)nc_d;
        const float tr  = (na * nb * nc) /
                          ((na + 1e-8f) * (nb + 1e-8f) * (nc + 1e-8f));
        const float dev = fabsf(tr - rintf(tr));
        ok = (dev <= 0.1f) && (tr <= 1.5f);
      }
      if (ok) { found = true; break; }
      ++fails;
    }
    aborts += fails;

    if (found) {
      const double Ewin = __shfl(Ej, p);
      minE = fmin(minE, Ewin);
      const bool closed = (cand == start) && (plen > 2);
      prev = cur; cur = cand; plen += 1;
      na_d = nb_d; nb_d = nc_d;
      if (closed) { if (minE < E_THRESH) detected = true; break; }
    } else {
      ++restarts;
      uint32_t h0 = 0u, h1 = 0u; tf2x32(kr0, kr1, h0, h1);
      uint32_t l0 = 0u, l1 = 1u; tf2x32(kr0, kr1, l0, l1);
      const uint32_t hi = tf_fold(h0, h1, 0u, 0u);
      const uint32_t lo = tf_fold(l0, l1, 0u, 0u);
      const uint32_t span = (uint32_t)nv;
      uint32_t mult = (65536u % span); mult = (mult * mult) % span;
      const uint32_t r = ((hi % span) * mult + (lo % span)) % span;
      const int node = viol[r];
      cur = node; prev = node; plen = 1;
      na_d = sumsq[node]; nb_d = na_d;
    }
    key0 = __builtin_amdgcn_readfirstlane(nk0);
    key1 = __builtin_amdgcn_readfirstlane(nk1);
  }

  if (lane == 0) {
    if (detected)      atomicOr(&out[v], 1);
    if (aborts != 0)   atomicAdd(&out[nv], aborts);
    if (restarts != 0) atomicAdd(&out[nv + 1], restarts);
  }
}

// ---- fallback: round-1 in-walk dot kernel (only if ws too small) -----------
__global__ __launch_bounds__(256) void walk_ref_kernel(
    const float* __restrict__ H, const int* __restrict__ viol,
    const double* __restrict__ sumsq, int* __restrict__ out,
    int nv, int seq_len) {
  const int wave = (int)((blockIdx.x * blockDim.x + threadIdx.x) >> 6);
  const int lane = threadIdx.x & 63;
  if (wave >= nv * NUM_WALKS) return;
  const int v     = wave / NUM_WALKS;
  const int start = viol[v];
  uint32_t key0 = 0u, key1 = (uint32_t)wave;
  tf2x32(0u, 42u, key0, key1);
  const float4* __restrict__ H4 = (const float4*)H;
  int    cur = start, prev = start, plen = 1;
  double min_sim = 1e9;
  bool   detected = false;
  int    aborts = 0, restarts = 0;
  for (int step = 0; step < WALK_LEN; ++step) {
    uint32_t nk0 = 0u, nk1 = 0u; tf2x32(key0, key1, nk0, nk1);
    uint32_t ks0 = 0u, ks1 = 1u; tf2x32(key0, key1, ks0, ks1);
    uint32_t kr0 = 0u, kr1 = 2u; tf2x32(key0, key1, kr0, kr1);
    const double ncur = sqrt(sumsq[cur]) + 1e-8;
    double a[16];
    {
      const float4* rc = H4 + ((size_t)cur << 8);
#pragma unroll
      for (int k = 0; k < 4; ++k) {
        float4 x = rc[lane + (k << 6)];
        a[4*k+0] = x.x; a[4*k+1] = x.y; a[4*k+2] = x.z; a[4*k+3] = x.w;
      }
    }
    double my_sim = 0.0;
    for (int jj = 0; jj < 33; ++jj) {
      const int idx = cur - HALF_WIN + jj;
      if (jj == HALF_WIN || idx < 0 || idx >= seq_len) continue;
      const float4* rb = H4 + ((size_t)idx << 8);
      double acc = 0.0;
#pragma unroll
      for (int k = 0; k < 4; ++k) {
        float4 x = rb[lane + (k << 6)];
        acc += a[4*k+0] * (double)x.x + a[4*k+1] * (double)x.y
             + a[4*k+2] * (double)x.z + a[4*k+3] * (double)x.w;
      }
#pragma unroll
      for (int off = 32; off; off >>= 1) acc += __shfl_xor(acc, off);
      const double s = acc / (ncur * (sqrt(sumsq[idx]) + 1e-8));
      if (lane == jj) my_sim = s;
    }
    bool found = false; int fails = 0, p = 0, cand = 0;
    const int  myidx   = cur - HALF_WIN + lane;
    const bool myvalid = (lane < 33) && (lane != HALF_WIN) &&
                         (myidx >= 0) && (myidx < seq_len);
    for (int at = 0; at < 3; ++at) {
      uint32_t s0 = 0u, s1 = (uint32_t)at; tf2x32(ks0, ks1, s0, s1);
      double z; int bi;
      if (myvalid) {
        const uint32_t bits = tf_fold(s0, s1, 0u, (uint32_t)lane);
        const uint32_t fb   = (bits >> 9) | 0x3f800000u;
        const float    f    = __uint_as_float(fb) - 1.0f;
        const float    u    = (f > 0.0f) ? f : 1.1754943508222875e-38f;
        const double   g    = -log(-log((double)u));
        z  = g + 5.0 * my_sim;
        bi = lane;
      } else { z = -1e300; bi = 1000; }
#pragma unroll
      for (int off = 32; off; off >>= 1) {
        const double oz = __shfl_xor(z, off);
        const int    oi = __shfl_xor(bi, off);
        if (oz > z || (oz == z && oi < bi)) { z = oz; bi = oi; }
      }
      p    = bi;
      cand = cur - HALF_WIN + p;
      bool ok;
      if (plen < 2) ok = true;
      else {
        const float na = (float)sumsq[prev], nb = (float)sumsq[cur],
                    nc = (float)sumsq[cand];
        const float tr  = (na * nb * nc) /
                          ((na + 1e-8f) * (nb + 1e-8f) * (nc + 1e-8f));
        const float dev = fabsf(tr - rintf(tr));
        ok = (dev <= 0.1f) && (tr <= 1.5f);
      }
      if (ok) { found = true; break; }
      ++fails;
    }
    aborts += fails;
    if (found) {
      const double sim = __shfl(my_sim, p);
      const double nm  = fmin(min_sim, sim);
      const bool closed = (cand == start) && (plen > 2);
      prev = cur; cur = cand; plen += 1; min_sim = nm;
      if (closed) { if (nm < 0.1) detected = true; break; }
    } else {
      ++restarts;
      uint32_t h0 = 0u, h1 = 0u; tf2x32(kr0, kr1, h0, h1);
      uint32_t l0 = 0u, l1 = 1u; tf2x32(kr0, kr1, l0, l1);
      const uint32_t hi = tf_fold(h0, h1, 0u, 0u);
      const uint32_t lo = tf_fold(l0, l1, 0u, 0u);
      const uint32_t span = (uint32_t)nv;
      uint32_t mult = (65536u % span); mult = (mult * mult) % span;
      const uint32_t r = ((hi % span) * mult + (lo % span)) % span;
      const int node = viol[r];
      cur = node; prev = node; plen = 1;
    }
    key0 = nk0; key1 = nk1;
  }
  if (lane == 0) {
    if (detected)      atomicOr(&out[v], 1);
    if (aborts != 0)   atomicAdd(&out[nv], aborts);
    if (restarts != 0) atomicAdd(&out[nv + 1], restarts);
  }
}

extern "C" void kernel_launch(void* const* d_in, const int* in_sizes, int n_in,
                              void* d_out, int out_size, void* d_ws, size_t ws_size,
                              hipStream_t stream) {
  const float* H    = (const float*)d_in[0];
  const int*   viol = (const int*)d_in[1];
  const int    nv      = in_sizes[1];
  const int    seq_len = in_sizes[0] / HID;
  const int    nwalks  = nv * NUM_WALKS;

  double* sumsq = (double*)d_ws;                       // seq_len * 8 B
  double* Etab  = (double*)((char*)d_ws + (size_t)seq_len * sizeof(double));
  const size_t need2 = (size_t)seq_len * sizeof(double)
                     + (size_t)seq_len * 33 * sizeof(double);
  double* Wtab  = (double*)((char*)d_ws + need2);
  const size_t needW = need2
                     + (size_t)nwalks * WALK_LEN * 32 * sizeof(double);

  const int wblocks = (nwalks + 3) / 4;

  if (ws_size >= needW) {
    const int npairs  = (nwalks + 1) / 2;
    const int rblocks = (npairs + 3) / 4;
    rng_w_kernel<<<rblocks, 256, 0, stream>>>(Wtab, nwalks);
    const int blocks = (seq_len + CENTERS - 1) / CENTERS;   // 512 @ 8192
    band_fused_kernel<<<blocks, 512, 0, stream>>>(H, sumsq, Etab,
                                                  (int*)d_out, out_size,
                                                  seq_len);
    walk_tab_kernel<<<wblocks, 256, 0, stream>>>(Etab, sumsq, Wtab, viol,
                                                 (int*)d_out, nv, seq_len);
  } else if (ws_size >= need2) {
    const int blocks = (seq_len + CENTERS - 1) / CENTERS;
    band_fused_kernel<<<blocks, 512, 0, stream>>>(H, sumsq, Etab,
                                                  (int*)d_out, out_size,
                                                  seq_len);
    walk_fast_kernel<<<wblocks, 256, 0, stream>>>(Etab, sumsq, viol,
                                                  (int*)d_out, nv, seq_len);
  } else {
    const int blocks = (seq_len + 3) / 4;
    rowsq_kernel<<<blocks, 256, 0, stream>>>(H, sumsq, (int*)d_out,
                                             out_size, seq_len);
    walk_ref_kernel<<<wblocks, 256, 0, stream>>>(H, viol, sumsq,
                                                 (int*)d_out, nv, seq_len);
  }
}

// Round 8
// 66.125 us; speedup vs baseline: 1.1762x; 1.1489x over previous
//
#include <hip/hip_runtime.h>
#include <stdint.h>
#include <math.h>

// ---------------------------------------------------------------------------
// SparseExplorerRouting, round 11.
//
// Carried facts (R1-R3, R5 PASSED absmax 0; R4/R6/R7 regressed; R8-R10 ~neutral):
//   * jax_threefry_partitionable=True counter scheme; key(42) -> (0,42);
//     walk (v,w) = split child v*5+w; per-step children ctr (0,{0,1,2}).
//   * output int32 {flags[1024], sum_aborts, sum_restarts}.
//   * f64 analog proxy passes with margin; ~1e-15 w-perturbations proven
//     safe on HW (R9/R10 fast_neg_log table paths passed absmax 0).
//   * E-table argmax(E/w) trick, w=-log(u); minE<e^0.5 == min_sim<0.1.
//   * EMPIRICAL LAW (R5/R8/R9/R10): producing the 41k wave-rows of w costs
//     25-33us in ANY separate producer; cheapest in-walk (25.6 marginal,
//     overlaps walk's memory stalls). Table configs net-lose: 76 vs 68.
//   * R5 band (512thr, unrolled d-loop, 131KB LDS) = 25.9us: KEEPER.
//   * Walk's in-loop libm f64 log ~600cy/step = the biggest VALU item.
//
// Round 11 changes (band = R5 verbatim; walk restructured):
//   * walk_pre_kernel: w-production HOISTED to a register prologue --
//     invw[8] = 1/fast_neg_log(bits) per lane (16 VGPR), key chain fully
//     precomputed (k0s/k1s[8] in SGPRs for rare cold paths). Step loop
//     FULLY UNROLLED (static invw/key indexing; rule: runtime-indexed
//     locals spill). Hot loop body = E-load, sq-load, f = Ej*invw[step],
//     butterfly, cycle check, update. No in-loop threefry, no log, no div.
//   * 8 independent log chains overlap E-load stalls across 5 waves/SIMD
//     (R5's overlap benefit without its on-critical-path log).
//   * rng kernel + Wtab DELETED. Two kernels: attribution is total-25.9.
// ---------------------------------------------------------------------------

#define HID        1024
#define NUM_WALKS  5
#define WALK_LEN   8
#define HALF_WIN   16
#define E_THRESH   1.6487212707001282   // exp(0.5) = exp(5 * BIRTH_DEATH_EPS)

#define CENTERS    16                   // centers per band block
#define SROWS      32                   // staged rows = CENTERS + 16 halo

__device__ __forceinline__ void tf2x32(uint32_t k0, uint32_t k1,
                                       uint32_t& x0, uint32_t& x1) {
  uint32_t ks2 = k0 ^ k1 ^ 0x1BD11BDAu;
  x0 += k0; x1 += k1;
#define TFR(r) { x0 += x1; x1 = (x1 << (r)) | (x1 >> (32 - (r))); x1 ^= x0; }
  TFR(13) TFR(15) TFR(26) TFR(6)
  x0 += k1;  x1 += ks2 + 1u;
  TFR(17) TFR(29) TFR(16) TFR(24)
  x0 += ks2; x1 += k0 + 2u;
  TFR(13) TFR(15) TFR(26) TFR(6)
  x0 += k0;  x1 += k1 + 3u;
  TFR(17) TFR(29) TFR(16) TFR(24)
  x0 += k1;  x1 += ks2 + 4u;
  TFR(13) TFR(15) TFR(26) TFR(6)
  x0 += ks2; x1 += k0 + 5u;
#undef TFR
}

__device__ __forceinline__ uint32_t tf_fold(uint32_t k0, uint32_t k1,
                                            uint32_t c0, uint32_t c1) {
  tf2x32(k0, k1, c0, c1);
  return c0 ^ c1;
}

// fast f64 w = -log(u), u = k*2^-23 (k = bits>>9). HW-validated (R9/R10).
__device__ __forceinline__ double fast_neg_log(uint32_t bits) {
  const uint32_t k  = bits >> 9;
  const uint32_t kk = k ? k : 1u;
  const int e = 31 - __clz((int)kk);          // 0..22
  const uint64_t mant = (((uint64_t)kk) << (52 - e)) & 0x000FFFFFFFFFFFFFULL;
  double m = __longlong_as_double(0x3FF0000000000000ULL | mant);  // [1,2)
  double E = (double)(e - 23);
  const bool hi = (m >= 1.4142135623730951);
  m = hi ? m * 0.5 : m;
  E = hi ? E + 1.0 : E;
  const double r  = (m - 1.0) / (m + 1.0);
  const double r2 = r * r;
  double p =            1.0/25.0;
  p = 1.0/23.0 + r2*p;
  p = 1.0/21.0 + r2*p;
  p = 1.0/19.0 + r2*p;
  p = 1.0/17.0 + r2*p;
  p = 1.0/15.0 + r2*p;
  p = 1.0/13.0 + r2*p;
  p = 1.0/11.0 + r2*p;
  p = 1.0/9.0  + r2*p;
  p = 1.0/7.0  + r2*p;
  p = 1.0/5.0  + r2*p;
  p = 1.0/3.0  + r2*p;
  p = 1.0      + r2*p;
  const double w = -(E * 0.6931471805599453 + 2.0 * r * p);
  return k ? w : 87.33654475055310899;        // -log(2^-126)
}

// ---- fused band + rowsq + d_out zeroing (R5 512-thread form, verbatim) -----
__global__ __launch_bounds__(512) void band_fused_kernel(
    const float* __restrict__ H, double* __restrict__ sumsq,
    double* __restrict__ E, int* __restrict__ out, int out_n, int seq_len) {
  __shared__ __align__(16) float  tile[SROWS][HID];   // 128 KB
  __shared__ double ssq[SROWS];

  if (blockIdx.x == 0) {                 // fold d_out zeroing in (dispatch
    for (int t = threadIdx.x; t < out_n; t += 512) out[t] = 0;   // ordering
  }                                      // guarantees walk sees zeros)

  int wg = blockIdx.x;
  {
    const int nwg = gridDim.x;           // bijective XCD swizzle (nwg%8==0)
    if ((nwg & 7) == 0) wg = (wg & 7) * (nwg >> 3) + (wg >> 3);
  }
  const int wid  = (int)(threadIdx.x >> 6);   // 0..7
  const int lane = (int)(threadIdx.x & 63);
  const int i0   = wg * CENTERS;
  const float4* __restrict__ H4 = (const float4*)H;

  // ---- stage 4 rows per wave + sumsq (same order as old rowsq) ----
#pragma unroll
  for (int rr = 0; rr < 4; ++rr) {
    const int local = wid * 4 + rr;      // wave-uniform
    const int row   = i0 + local;
    if (row < seq_len) {
      const float4* src = H4 + ((size_t)row << 8);
      float4* dst = (float4*)&tile[local][0];
      double acc = 0.0;
#pragma unroll
      for (int k = 0; k < 4; ++k) {
        float4 x = src[lane + (k << 6)];
        dst[lane + (k << 6)] = x;
        acc += (double)x.x * x.x + (double)x.y * x.y
             + (double)x.z * x.z + (double)x.w * x.w;
      }
#pragma unroll
      for (int off = 32; off; off >>= 1) acc += __shfl_xor(acc, off);
      if (lane == 0) {
        ssq[local] = acc;
        if (local < CENTERS) sumsq[row] = acc;   // each row owned by 1 block
      }
    }
  }
  __syncthreads();

  // ---- 2 centers per wave, 16 forward dots each, from LDS ----
#pragma unroll
  for (int cc = 0; cc < 2; ++cc) {
    const int cl = wid * 2 + cc;         // 0..15, wave-uniform
    const int i  = i0 + cl;
    if (i >= seq_len) continue;

    double a[16];
    {
      const float4* rc = (const float4*)&tile[cl][0];
#pragma unroll
      for (int k = 0; k < 4; ++k) {
        float4 x = rc[lane + (k << 6)];
        a[4*k+0] = x.x; a[4*k+1] = x.y; a[4*k+2] = x.z; a[4*k+3] = x.w;
      }
    }
    const double ni = sqrt(ssq[cl]) + 1e-8;

    // d-loop fully unrolled: p[] indices static -> registers, no scratch.
    // Halo garbage (i+d >= seq_len) stays segregated per-d and never
    // reaches the guarded write. Bit-identical valid E.
    double p[16];
#pragma unroll
    for (int d = 0; d < 16; ++d) p[d] = 0.0;
#pragma unroll
    for (int d = 1; d <= 16; ++d) {
      const float4* rb = (const float4*)&tile[cl + d][0];
#pragma unroll
      for (int k = 0; k < 4; ++k) {
        float4 x = rb[lane + (k << 6)];
        p[d-1] += a[4*k+0] * (double)x.x + a[4*k+1] * (double)x.y
                + a[4*k+2] * (double)x.z + a[4*k+3] * (double)x.w;
      }
    }

    // multi-value reduce-scatter: value bit3..0 <- lane bit5..2
#pragma unroll
    for (int v = 0; v < 8; ++v) {                     // stage xor 32
      double send = (lane & 32) ? p[v] : p[v+8];
      double recv = __shfl_xor(send, 32);
      double mine = (lane & 32) ? p[v+8] : p[v];
      p[v] = mine + recv;
    }
#pragma unroll
    for (int v = 0; v < 4; ++v) {                     // stage xor 16
      double send = (lane & 16) ? p[v] : p[v+4];
      double recv = __shfl_xor(send, 16);
      double mine = (lane & 16) ? p[v+4] : p[v];
      p[v] = mine + recv;
    }
#pragma unroll
    for (int v = 0; v < 2; ++v) {                     // stage xor 8
      double send = (lane & 8) ? p[v] : p[v+2];
      double recv = __shfl_xor(send, 8);
      double mine = (lane & 8) ? p[v+2] : p[v];
      p[v] = mine + recv;
    }
    {                                                 // stage xor 4
      double send = (lane & 4) ? p[0] : p[1];
      double recv = __shfl_xor(send, 4);
      double mine = (lane & 4) ? p[1] : p[0];
      p[0] = mine + recv;
    }
    p[0] += __shfl_xor(p[0], 2);                      // stage xor 2
    p[0] += __shfl_xor(p[0], 1);                      // stage xor 1

    const int v = ((lane >> 2) & 1) | (((lane >> 3) & 1) << 1)
                | (((lane >> 4) & 1) << 2) | (((lane >> 5) & 1) << 3);
    const int d = v + 1;
    if ((lane & 3) == 0 && i + d < seq_len) {
      const double s  = p[0] / (ni * (sqrt(ssq[cl + d]) + 1e-8));
      const double Ev = exp(5.0 * s);
      E[(size_t)i * 33 + 16 + d]       = Ev;
      E[(size_t)(i + d) * 33 + 16 - d] = Ev;
    }
  }
}

// ---- per-row sum of squares (f64) + d_out zeroing (fallback tier only) -----
__global__ __launch_bounds__(256) void rowsq_kernel(
    const float* __restrict__ H, double* __restrict__ sumsq,
    int* __restrict__ out, int out_n, int seq_len) {
  if (blockIdx.x == 0) {
    for (int t = threadIdx.x; t < out_n; t += 256) out[t] = 0;
  }
  const int row  = (int)((blockIdx.x * blockDim.x + threadIdx.x) >> 6);
  const int lane = threadIdx.x & 63;
  if (row >= seq_len) return;
  const float4* r = (const float4*)(H + (size_t)row * HID);
  double acc = 0.0;
#pragma unroll
  for (int k = 0; k < 4; ++k) {
    float4 x = r[lane + (k << 6)];
    acc += (double)x.x * x.x + (double)x.y * x.y
         + (double)x.z * x.z + (double)x.w * x.w;
  }
#pragma unroll
  for (int off = 32; off; off >>= 1) acc += __shfl_xor(acc, off);
  if (lane == 0) sumsq[row] = acc;
}

// ---- walk kernel: register-prologue w, fully unrolled step loop ------------
__global__ __launch_bounds__(256) void walk_pre_kernel(
    const double* __restrict__ E, const double* __restrict__ sumsq,
    const int* __restrict__ viol, int* __restrict__ out,
    int nv, int seq_len) {
  int wave = (int)((blockIdx.x * blockDim.x + threadIdx.x) >> 6);
  const int lane = threadIdx.x & 63;
  if (wave >= nv * NUM_WALKS) return;
  wave = __builtin_amdgcn_readfirstlane(wave);
  const int v     = wave / NUM_WALKS;
  const int start = viol[v];

  uint32_t key0 = 0u, key1 = (uint32_t)wave;
  tf2x32(0u, 42u, key0, key1);
  key0 = __builtin_amdgcn_readfirstlane(key0);
  key1 = __builtin_amdgcn_readfirstlane(key1);

  // ---- prologue: full key chain (SGPRs) + per-lane invw[8] (VGPRs) ----
  // w values identical to R9/R10's table (same fast_neg_log); invw adds
  // 1 ulp to the pick quantity only (argmax-safe, margins O(1)).
  uint32_t k0s[WALK_LEN], k1s[WALK_LEN];
  double   invw[WALK_LEN];
#pragma unroll
  for (int s = 0; s < WALK_LEN; ++s) {
    k0s[s] = key0; k1s[s] = key1;
    uint32_t nk0 = 0u, nk1 = 0u; tf2x32(key0, key1, nk0, nk1);
    uint32_t ks0 = 0u, ks1 = 1u; tf2x32(key0, key1, ks0, ks1);
    uint32_t s0  = 0u, s1  = 0u; tf2x32(ks0, ks1, s0, s1);   // attempt 0
    const uint32_t bits = tf_fold(s0, s1, 0u, (uint32_t)lane);
    invw[s] = 1.0 / fast_neg_log(bits);
    key0 = __builtin_amdgcn_readfirstlane(nk0);
    key1 = __builtin_amdgcn_readfirstlane(nk1);
  }

  int    cur = start, prev = start, plen = 1;
  double minE = 1e300;
  bool   detected = false;
  int    aborts = 0, restarts = 0;
  // carried |h|^2 of prev / cur (identical doubles to sumsq[] entries)
  double na_d = sumsq[start], nb_d = na_d;

#pragma unroll
  for (int step = 0; step < WALK_LEN; ++step) {
    const int  myidx   = cur - HALF_WIN + lane;
    const bool myvalid = (lane < 33) && (lane != HALF_WIN) &&
                         (myidx >= 0) && (myidx < seq_len);
    const int  clipped = myidx < 0 ? 0 : (myidx >= seq_len ? seq_len - 1 : myidx);
    const double Ej = E[(size_t)cur * 33 + (lane < 33 ? lane : 0)];
    const double sq_win = sumsq[clipped];   // window |h|^2, issued with Ej

    bool found = false; int fails = 0, p = 0, cand = 0;
    double nc_d = 0.0;
    for (int at = 0; at < 3; ++at) {
      double f; int bi;
      if (myvalid) {
        if (at == 0) {
          f = Ej * invw[step];  // hot path: no threefry, no log, no div
        } else {                // cold path (rare): recompute from saved key
          uint32_t ks0 = 0u, ks1 = 1u; tf2x32(k0s[step], k1s[step], ks0, ks1);
          uint32_t s0 = 0u, s1 = (uint32_t)at; tf2x32(ks0, ks1, s0, s1);
          const uint32_t bits = tf_fold(s0, s1, 0u, (uint32_t)lane);
          f = Ej / fast_neg_log(bits);
        }
        bi = lane;
      } else { f = -1.0; bi = 1000; }
#pragma unroll
      for (int off = 32; off; off >>= 1) {
        const double of = __shfl_xor(f, off);
        const int    oi = __shfl_xor(bi, off);
        if (of > f || (of == f && oi < bi)) { f = of; bi = oi; }
      }
      p    = bi;
      cand = cur - HALF_WIN + p;
      nc_d = __shfl(sq_win, p);     // == sumsq[cand], no dependent load
      bool ok;
      if (plen < 2) ok = true;
      else {
        const float na = (float)na_d, nb = (float)nb_d, nc = (float)nc_d;
        const float tr  = (na * nb * nc) /
                          ((na + 1e-8f) * (nb + 1e-8f) * (nc + 1e-8f));
        const float dev = fabsf(tr - rintf(tr));
        ok = (dev <= 0.1f) && (tr <= 1.5f);
      }
      if (ok) { found = true; break; }
      ++fails;
    }
    aborts += fails;

    if (found) {
      const double Ewin = __shfl(Ej, p);
      minE = fmin(minE, Ewin);
      const bool closed = (cand == start) && (plen > 2);
      prev = cur; cur = cand; plen += 1;
      na_d = nb_d; nb_d = nc_d;
      if (closed) { if (minE < E_THRESH) detected = true; break; }
    } else {
      ++restarts;                 // rare path: restart chain from saved key
      uint32_t kr0 = 0u, kr1 = 2u; tf2x32(k0s[step], k1s[step], kr0, kr1);
      uint32_t h0 = 0u, h1 = 0u; tf2x32(kr0, kr1, h0, h1);
      uint32_t l0 = 0u, l1 = 1u; tf2x32(kr0, kr1, l0, l1);
      const uint32_t hi = tf_fold(h0, h1, 0u, 0u);
      const uint32_t lo = tf_fold(l0, l1, 0u, 0u);
      const uint32_t span = (uint32_t)nv;
      uint32_t mult = (65536u % span); mult = (mult * mult) % span;
      const uint32_t r = ((hi % span) * mult + (lo % span)) % span;
      const int node = viol[r];
      cur = node; prev = node; plen = 1;
      na_d = sumsq[node]; nb_d = na_d;
    }
  }

  if (lane == 0) {
    if (detected)      atomicOr(&out[v], 1);
    if (aborts != 0)   atomicAdd(&out[nv], aborts);
    if (restarts != 0) atomicAdd(&out[nv + 1], restarts);
  }
}

// ---- fallback: round-1 in-walk dot kernel (only if ws too small) -----------
__global__ __launch_bounds__(256) void walk_ref_kernel(
    const float* __restrict__ H, const int* __restrict__ viol,
    const double* __restrict__ sumsq, int* __restrict__ out,
    int nv, int seq_len) {
  const int wave = (int)((blockIdx.x * blockDim.x + threadIdx.x) >> 6);
  const int lane = threadIdx.x & 63;
  if (wave >= nv * NUM_WALKS) return;
  const int v     = wave / NUM_WALKS;
  const int start = viol[v];
  uint32_t key0 = 0u, key1 = (uint32_t)wave;
  tf2x32(0u, 42u, key0, key1);
  const float4* __restrict__ H4 = (const float4*)H;
  int    cur = start, prev = start, plen = 1;
  double min_sim = 1e9;
  bool   detected = false;
  int    aborts = 0, restarts = 0;
  for (int step = 0; step < WALK_LEN; ++step) {
    uint32_t nk0 = 0u, nk1 = 0u; tf2x32(key0, key1, nk0, nk1);
    uint32_t ks0 = 0u, ks1 = 1u; tf2x32(key0, key1, ks0, ks1);
    uint32_t kr0 = 0u, kr1 = 2u; tf2x32(key0, key1, kr0, kr1);
    const double ncur = sqrt(sumsq[cur]) + 1e-8;
    double a[16];
    {
      const float4* rc = H4 + ((size_t)cur << 8);
#pragma unroll
      for (int k = 0; k < 4; ++k) {
        float4 x = rc[lane + (k << 6)];
        a[4*k+0] = x.x; a[4*k+1] = x.y; a[4*k+2] = x.z; a[4*k+3] = x.w;
      }
    }
    double my_sim = 0.0;
    for (int jj = 0; jj < 33; ++jj) {
      const int idx = cur - HALF_WIN + jj;
      if (jj == HALF_WIN || idx < 0 || idx >= seq_len) continue;
      const float4* rb = H4 + ((size_t)idx << 8);
      double acc = 0.0;
#pragma unroll
      for (int k = 0; k < 4; ++k) {
        float4 x = rb[lane + (k << 6)];
        acc += a[4*k+0] * (double)x.x + a[4*k+1] * (double)x.y
             + a[4*k+2] * (double)x.z + a[4*k+3] * (double)x.w;
      }
#pragma unroll
      for (int off = 32; off; off >>= 1) acc += __shfl_xor(acc, off);
      const double s = acc / (ncur * (sqrt(sumsq[idx]) + 1e-8));
      if (lane == jj) my_sim = s;
    }
    bool found = false; int fails = 0, p = 0, cand = 0;
    const int  myidx   = cur - HALF_WIN + lane;
    const bool myvalid = (lane < 33) && (lane != HALF_WIN) &&
                         (myidx >= 0) && (myidx < seq_len);
    for (int at = 0; at < 3; ++at) {
      uint32_t s0 = 0u, s1 = (uint32_t)at; tf2x32(ks0, ks1, s0, s1);
      double z; int bi;
      if (myvalid) {
        const uint32_t bits = tf_fold(s0, s1, 0u, (uint32_t)lane);
        const uint32_t fb   = (bits >> 9) | 0x3f800000u;
        const float    f    = __uint_as_float(fb) - 1.0f;
        const float    u    = (f > 0.0f) ? f : 1.1754943508222875e-38f;
        const double   g    = -log(-log((double)u));
        z  = g + 5.0 * my_sim;
        bi = lane;
      } else { z = -1e300; bi = 1000; }
#pragma unroll
      for (int off = 32; off; off >>= 1) {
        const double oz = __shfl_xor(z, off);
        const int    oi = __shfl_xor(bi, off);
        if (oz > z || (oz == z && oi < bi)) { z = oz; bi = oi; }
      }
      p    = bi;
      cand = cur - HALF_WIN + p;
      bool ok;
      if (plen < 2) ok = true;
      else {
        const float na = (float)sumsq[prev], nb = (float)sumsq[cur],
                    nc = (float)sumsq[cand];
        const float tr  = (na * nb * nc) /
                          ((na + 1e-8f) * (nb + 1e-8f) * (nc + 1e-8f));
        const float dev = fabsf(tr - rintf(tr));
        ok = (dev <= 0.1f) && (tr <= 1.5f);
      }
      if (ok) { found = true; break; }
      ++fails;
    }
    aborts += fails;
    if (found) {
      const double sim = __shfl(my_sim, p);
      const double nm  = fmin(min_sim, sim);
      const bool closed = (cand == start) && (plen > 2);
      prev = cur; cur = cand; plen += 1; min_sim = nm;
      if (closed) { if (nm < 0.1) detected = true; break; }
    } else {
      ++restarts;
      uint32_t h0 = 0u, h1 = 0u; tf2x32(kr0, kr1, h0, h1);
      uint32_t l0 = 0u, l1 = 1u; tf2x32(kr0, kr1, l0, l1);
      const uint32_t hi = tf_fold(h0, h1, 0u, 0u);
      const uint32_t lo = tf_fold(l0, l1, 0u, 0u);
      const uint32_t span = (uint32_t)nv;
      uint32_t mult = (65536u % span); mult = (mult * mult) % span;
      const uint32_t r = ((hi % span) * mult + (lo % span)) % span;
      const int node = viol[r];
      cur = node; prev = node; plen = 1;
    }
    key0 = nk0; key1 = nk1;
  }
  if (lane == 0) {
    if (detected)      atomicOr(&out[v], 1);
    if (aborts != 0)   atomicAdd(&out[nv], aborts);
    if (restarts != 0) atomicAdd(&out[nv + 1], restarts);
  }
}

extern "C" void kernel_launch(void* const* d_in, const int* in_sizes, int n_in,
                              void* d_out, int out_size, void* d_ws, size_t ws_size,
                              hipStream_t stream) {
  const float* H    = (const float*)d_in[0];
  const int*   viol = (const int*)d_in[1];
  const int    nv      = in_sizes[1];
  const int    seq_len = in_sizes[0] / HID;
  const int    nwalks  = nv * NUM_WALKS;

  double* sumsq = (double*)d_ws;                       // seq_len * 8 B
  double* Etab  = (double*)((char*)d_ws + (size_t)seq_len * sizeof(double));
  const size_t need = (size_t)seq_len * sizeof(double)
                    + (size_t)seq_len * 33 * sizeof(double);

  const int wblocks = (nwalks + 3) / 4;

  if (ws_size >= need) {
    const int blocks = (seq_len + CENTERS - 1) / CENTERS;   // 512 @ 8192
    band_fused_kernel<<<blocks, 512, 0, stream>>>(H, sumsq, Etab,
                                                  (int*)d_out, out_size,
                                                  seq_len);
    walk_pre_kernel<<<wblocks, 256, 0, stream>>>(Etab, sumsq, viol,
                                                 (int*)d_out, nv, seq_len);
  } else {
    const int blocks = (seq_len + 3) / 4;
    rowsq_kernel<<<blocks, 256, 0, stream>>>(H, sumsq, (int*)d_out,
                                             out_size, seq_len);
    walk_ref_kernel<<<wblocks, 256, 0, stream>>>(H, viol, sumsq,
                                                 (int*)d_out, nv, seq_len);
  }
}

// Round 9
// 62.700 us; speedup vs baseline: 1.2405x; 1.0546x over previous
//
#include <hip/hip_runtime.h>
#include <stdint.h>
#include <math.h>

// ---------------------------------------------------------------------------
// SparseExplorerRouting, round 12.
//
// Carried facts (best = R11 66.1us; R1-R3/R5/R9-R11 PASSED absmax 0):
//   * jax_threefry_partitionable=True counter scheme; key(42) -> (0,42);
//     walk (v,w) = split child v*5+w; per-step children ctr (0,{0,1,2}).
//   * output int32 {flags[1024], sum_aborts, sum_restarts}.
//   * E-table argmax(E/w) trick, w=-log(u); minE<e^0.5 == min_sim<0.1.
//   * EMPIRICAL LAW: producing the 41k wave-rows of w costs ~25us with
//     f64 log of ANY implementation (libm / custom poly+div), anywhere
//     (R5 in-loop, R8/R9/R10 producers, R11 prologue). f64 pipe (1/4 rate)
//     + f64 div + deep Horner chain is the cost, not the placement.
//   * R11 walk_pre (prologue w, unrolled steps) = 40.2us; walk base 16.6.
//   * R5 band (512thr, unrolled d-loop, 131KB LDS) = 25.9us: KEEPER.
//   * PRECISION: the reference computes -log(u) in f32 (~1e-7 rel err);
//     our exact-f64 w differs from it by the same ~1e-7 and passes bit-
//     exact -> argmax margins tolerate ~1e-7 w-perturbation on this data.
//
// Round 12 change (walk w-production only; band/hot-loop untouched):
//   * w via HW transcendental: u = k*2^-23 is EXACT in f32 (k < 2^24), so
//     w = -(f64)__log2f(u) * ln2. One v_log_f32 (~1ulp, 6e-8 rel — inside
//     the proven-tolerant 1e-7 ball) replaces the f64 div + 12-term f64
//     Horner: ~450cy -> ~160cy per value. Same function used in prologue
//     and all cold paths. Revert to R11 if absmax > 0.
// ---------------------------------------------------------------------------

#define HID        1024
#define NUM_WALKS  5
#define WALK_LEN   8
#define HALF_WIN   16
#define E_THRESH   1.6487212707001282   // exp(0.5) = exp(5 * BIRTH_DEATH_EPS)

#define CENTERS    16                   // centers per band block
#define SROWS      32                   // staged rows = CENTERS + 16 halo

__device__ __forceinline__ void tf2x32(uint32_t k0, uint32_t k1,
                                       uint32_t& x0, uint32_t& x1) {
  uint32_t ks2 = k0 ^ k1 ^ 0x1BD11BDAu;
  x0 += k0; x1 += k1;
#define TFR(r) { x0 += x1; x1 = (x1 << (r)) | (x1 >> (32 - (r))); x1 ^= x0; }
  TFR(13) TFR(15) TFR(26) TFR(6)
  x0 += k1;  x1 += ks2 + 1u;
  TFR(17) TFR(29) TFR(16) TFR(24)
  x0 += ks2; x1 += k0 + 2u;
  TFR(13) TFR(15) TFR(26) TFR(6)
  x0 += k0;  x1 += k1 + 3u;
  TFR(17) TFR(29) TFR(16) TFR(24)
  x0 += k1;  x1 += ks2 + 4u;
  TFR(13) TFR(15) TFR(26) TFR(6)
  x0 += ks2; x1 += k0 + 5u;
#undef TFR
}

__device__ __forceinline__ uint32_t tf_fold(uint32_t k0, uint32_t k1,
                                            uint32_t c0, uint32_t c1) {
  tf2x32(k0, k1, c0, c1);
  return c0 ^ c1;
}

// w = -log(u), u = k*2^-23 (k = bits>>9), via HW v_log_f32.
// (float)k exact (k<2^24); *2^-23 exact; log2f ~1ulp (6e-8 rel) -- inside
// the proven-tolerant ~1e-7 perturbation ball (see header).
__device__ __forceinline__ double fast_neg_log(uint32_t bits) {
  const uint32_t k = bits >> 9;
  if (k == 0) return 87.33654475055310899;    // -log(2^-126) clamp
  const float u  = (float)k * 1.1920928955078125e-7f;   // k * 2^-23, exact
  const float l2 = __log2f(u);                          // v_log_f32
  return (double)l2 * -0.6931471805599453;
}

// ---- fused band + rowsq + d_out zeroing (R5 512-thread form, verbatim) -----
__global__ __launch_bounds__(512) void band_fused_kernel(
    const float* __restrict__ H, double* __restrict__ sumsq,
    double* __restrict__ E, int* __restrict__ out, int out_n, int seq_len) {
  __shared__ __align__(16) float  tile[SROWS][HID];   // 128 KB
  __shared__ double ssq[SROWS];

  if (blockIdx.x == 0) {                 // fold d_out zeroing in (dispatch
    for (int t = threadIdx.x; t < out_n; t += 512) out[t] = 0;   // ordering
  }                                      // guarantees walk sees zeros)

  int wg = blockIdx.x;
  {
    const int nwg = gridDim.x;           // bijective XCD swizzle (nwg%8==0)
    if ((nwg & 7) == 0) wg = (wg & 7) * (nwg >> 3) + (wg >> 3);
  }
  const int wid  = (int)(threadIdx.x >> 6);   // 0..7
  const int lane = (int)(threadIdx.x & 63);
  const int i0   = wg * CENTERS;
  const float4* __restrict__ H4 = (const float4*)H;

  // ---- stage 4 rows per wave + sumsq (same order as old rowsq) ----
#pragma unroll
  for (int rr = 0; rr < 4; ++rr) {
    const int local = wid * 4 + rr;      // wave-uniform
    const int row   = i0 + local;
    if (row < seq_len) {
      const float4* src = H4 + ((size_t)row << 8);
      float4* dst = (float4*)&tile[local][0];
      double acc = 0.0;
#pragma unroll
      for (int k = 0; k < 4; ++k) {
        float4 x = src[lane + (k << 6)];
        dst[lane + (k << 6)] = x;
        acc += (double)x.x * x.x + (double)x.y * x.y
             + (double)x.z * x.z + (double)x.w * x.w;
      }
#pragma unroll
      for (int off = 32; off; off >>= 1) acc += __shfl_xor(acc, off);
      if (lane == 0) {
        ssq[local] = acc;
        if (local < CENTERS) sumsq[row] = acc;   // each row owned by 1 block
      }
    }
  }
  __syncthreads();

  // ---- 2 centers per wave, 16 forward dots each, from LDS ----
#pragma unroll
  for (int cc = 0; cc < 2; ++cc) {
    const int cl = wid * 2 + cc;         // 0..15, wave-uniform
    const int i  = i0 + cl;
    if (i >= seq_len) continue;

    double a[16];
    {
      const float4* rc = (const float4*)&tile[cl][0];
#pragma unroll
      for (int k = 0; k < 4; ++k) {
        float4 x = rc[lane + (k << 6)];
        a[4*k+0] = x.x; a[4*k+1] = x.y; a[4*k+2] = x.z; a[4*k+3] = x.w;
      }
    }
    const double ni = sqrt(ssq[cl]) + 1e-8;

    // d-loop fully unrolled: p[] indices static -> registers, no scratch.
    // Halo garbage (i+d >= seq_len) stays segregated per-d and never
    // reaches the guarded write. Bit-identical valid E.
    double p[16];
#pragma unroll
    for (int d = 0; d < 16; ++d) p[d] = 0.0;
#pragma unroll
    for (int d = 1; d <= 16; ++d) {
      const float4* rb = (const float4*)&tile[cl + d][0];
#pragma unroll
      for (int k = 0; k < 4; ++k) {
        float4 x = rb[lane + (k << 6)];
        p[d-1] += a[4*k+0] * (double)x.x + a[4*k+1] * (double)x.y
                + a[4*k+2] * (double)x.z + a[4*k+3] * (double)x.w;
      }
    }

    // multi-value reduce-scatter: value bit3..0 <- lane bit5..2
#pragma unroll
    for (int v = 0; v < 8; ++v) {                     // stage xor 32
      double send = (lane & 32) ? p[v] : p[v+8];
      double recv = __shfl_xor(send, 32);
      double mine = (lane & 32) ? p[v+8] : p[v];
      p[v] = mine + recv;
    }
#pragma unroll
    for (int v = 0; v < 4; ++v) {                     // stage xor 16
      double send = (lane & 16) ? p[v] : p[v+4];
      double recv = __shfl_xor(send, 16);
      double mine = (lane & 16) ? p[v+4] : p[v];
      p[v] = mine + recv;
    }
#pragma unroll
    for (int v = 0; v < 2; ++v) {                     // stage xor 8
      double send = (lane & 8) ? p[v] : p[v+2];
      double recv = __shfl_xor(send, 8);
      double mine = (lane & 8) ? p[v+2] : p[v];
      p[v] = mine + recv;
    }
    {                                                 // stage xor 4
      double send = (lane & 4) ? p[0] : p[1];
      double recv = __shfl_xor(send, 4);
      double mine = (lane & 4) ? p[1] : p[0];
      p[0] = mine + recv;
    }
    p[0] += __shfl_xor(p[0], 2);                      // stage xor 2
    p[0] += __shfl_xor(p[0], 1);                      // stage xor 1

    const int v = ((lane >> 2) & 1) | (((lane >> 3) & 1) << 1)
                | (((lane >> 4) & 1) << 2) | (((lane >> 5) & 1) << 3);
    const int d = v + 1;
    if ((lane & 3) == 0 && i + d < seq_len) {
      const double s  = p[0] / (ni * (sqrt(ssq[cl + d]) + 1e-8));
      const double Ev = exp(5.0 * s);
      E[(size_t)i * 33 + 16 + d]       = Ev;
      E[(size_t)(i + d) * 33 + 16 - d] = Ev;
    }
  }
}

// ---- per-row sum of squares (f64) + d_out zeroing (fallback tier only) -----
__global__ __launch_bounds__(256) void rowsq_kernel(
    const float* __restrict__ H, double* __restrict__ sumsq,
    int* __restrict__ out, int out_n, int seq_len) {
  if (blockIdx.x == 0) {
    for (int t = threadIdx.x; t < out_n; t += 256) out[t] = 0;
  }
  const int row  = (int)((blockIdx.x * blockDim.x + threadIdx.x) >> 6);
  const int lane = threadIdx.x & 63;
  if (row >= seq_len) return;
  const float4* r = (const float4*)(H + (size_t)row * HID);
  double acc = 0.0;
#pragma unroll
  for (int k = 0; k < 4; ++k) {
    float4 x = r[lane + (k << 6)];
    acc += (double)x.x * x.x + (double)x.y * x.y
         + (double)x.z * x.z + (double)x.w * x.w;
  }
#pragma unroll
  for (int off = 32; off; off >>= 1) acc += __shfl_xor(acc, off);
  if (lane == 0) sumsq[row] = acc;
}

// ---- walk kernel: register-prologue w (HW log), fully unrolled steps -------
__global__ __launch_bounds__(256) void walk_pre_kernel(
    const double* __restrict__ E, const double* __restrict__ sumsq,
    const int* __restrict__ viol, int* __restrict__ out,
    int nv, int seq_len) {
  int wave = (int)((blockIdx.x * blockDim.x + threadIdx.x) >> 6);
  const int lane = threadIdx.x & 63;
  if (wave >= nv * NUM_WALKS) return;
  wave = __builtin_amdgcn_readfirstlane(wave);
  const int v     = wave / NUM_WALKS;
  const int start = viol[v];

  uint32_t key0 = 0u, key1 = (uint32_t)wave;
  tf2x32(0u, 42u, key0, key1);
  key0 = __builtin_amdgcn_readfirstlane(key0);
  key1 = __builtin_amdgcn_readfirstlane(key1);

  // ---- prologue: full key chain (SGPRs) + per-lane invw[8] (VGPRs) ----
  uint32_t k0s[WALK_LEN], k1s[WALK_LEN];
  double   invw[WALK_LEN];
#pragma unroll
  for (int s = 0; s < WALK_LEN; ++s) {
    k0s[s] = key0; k1s[s] = key1;
    uint32_t nk0 = 0u, nk1 = 0u; tf2x32(key0, key1, nk0, nk1);
    uint32_t ks0 = 0u, ks1 = 1u; tf2x32(key0, key1, ks0, ks1);
    uint32_t s0  = 0u, s1  = 0u; tf2x32(ks0, ks1, s0, s1);   // attempt 0
    const uint32_t bits = tf_fold(s0, s1, 0u, (uint32_t)lane);
    invw[s] = 1.0 / fast_neg_log(bits);
    key0 = __builtin_amdgcn_readfirstlane(nk0);
    key1 = __builtin_amdgcn_readfirstlane(nk1);
  }

  int    cur = start, prev = start, plen = 1;
  double minE = 1e300;
  bool   detected = false;
  int    aborts = 0, restarts = 0;
  // carried |h|^2 of prev / cur (identical doubles to sumsq[] entries)
  double na_d = sumsq[start], nb_d = na_d;

#pragma unroll
  for (int step = 0; step < WALK_LEN; ++step) {
    const int  myidx   = cur - HALF_WIN + lane;
    const bool myvalid = (lane < 33) && (lane != HALF_WIN) &&
                         (myidx >= 0) && (myidx < seq_len);
    const int  clipped = myidx < 0 ? 0 : (myidx >= seq_len ? seq_len - 1 : myidx);
    const double Ej = E[(size_t)cur * 33 + (lane < 33 ? lane : 0)];
    const double sq_win = sumsq[clipped];   // window |h|^2, issued with Ej

    bool found = false; int fails = 0, p = 0, cand = 0;
    double nc_d = 0.0;
    for (int at = 0; at < 3; ++at) {
      double f; int bi;
      if (myvalid) {
        if (at == 0) {
          f = Ej * invw[step];  // hot path: no threefry, no log, no div
        } else {                // cold path (rare): recompute from saved key
          uint32_t ks0 = 0u, ks1 = 1u; tf2x32(k0s[step], k1s[step], ks0, ks1);
          uint32_t s0 = 0u, s1 = (uint32_t)at; tf2x32(ks0, ks1, s0, s1);
          const uint32_t bits = tf_fold(s0, s1, 0u, (uint32_t)lane);
          f = Ej / fast_neg_log(bits);
        }
        bi = lane;
      } else { f = -1.0; bi = 1000; }
#pragma unroll
      for (int off = 32; off; off >>= 1) {
        const double of = __shfl_xor(f, off);
        const int    oi = __shfl_xor(bi, off);
        if (of > f || (of == f && oi < bi)) { f = of; bi = oi; }
      }
      p    = bi;
      cand = cur - HALF_WIN + p;
      nc_d = __shfl(sq_win, p);     // == sumsq[cand], no dependent load
      bool ok;
      if (plen < 2) ok = true;
      else {
        const float na = (float)na_d, nb = (float)nb_d, nc = (float)nc_d;
        const float tr  = (na * nb * nc) /
                          ((na + 1e-8f) * (nb + 1e-8f) * (nc + 1e-8f));
        const float dev = fabsf(tr - rintf(tr));
        ok = (dev <= 0.1f) && (tr <= 1.5f);
      }
      if (ok) { found = true; break; }
      ++fails;
    }
    aborts += fails;

    if (found) {
      const double Ewin = __shfl(Ej, p);
      minE = fmin(minE, Ewin);
      const bool closed = (cand == start) && (plen > 2);
      prev = cur; cur = cand; plen += 1;
      na_d = nb_d; nb_d = nc_d;
      if (closed) { if (minE < E_THRESH) detected = true; break; }
    } else {
      ++restarts;                 // rare path: restart chain from saved key
      uint32_t kr0 = 0u, kr1 = 2u; tf2x32(k0s[step], k1s[step], kr0, kr1);
      uint32_t h0 = 0u, h1 = 0u; tf2x32(kr0, kr1, h0, h1);
      uint32_t l0 = 0u, l1 = 1u; tf2x32(kr0, kr1, l0, l1);
      const uint32_t hi = tf_fold(h0, h1, 0u, 0u);
      const uint32_t lo = tf_fold(l0, l1, 0u, 0u);
      const uint32_t span = (uint32_t)nv;
      uint32_t mult = (65536u % span); mult = (mult * mult) % span;
      const uint32_t r = ((hi % span) * mult + (lo % span)) % span;
      const int node = viol[r];
      cur = node; prev = node; plen = 1;
      na_d = sumsq[node]; nb_d = na_d;
    }
  }

  if (lane == 0) {
    if (detected)      atomicOr(&out[v], 1);
    if (aborts != 0)   atomicAdd(&out[nv], aborts);
    if (restarts != 0) atomicAdd(&out[nv + 1], restarts);
  }
}

// ---- fallback: round-1 in-walk dot kernel (only if ws too small) -----------
__global__ __launch_bounds__(256) void walk_ref_kernel(
    const float* __restrict__ H, const int* __restrict__ viol,
    const double* __restrict__ sumsq, int* __restrict__ out,
    int nv, int seq_len) {
  const int wave = (int)((blockIdx.x * blockDim.x + threadIdx.x) >> 6);
  const int lane = threadIdx.x & 63;
  if (wave >= nv * NUM_WALKS) return;
  const int v     = wave / NUM_WALKS;
  const int start = viol[v];
  uint32_t key0 = 0u, key1 = (uint32_t)wave;
  tf2x32(0u, 42u, key0, key1);
  const float4* __restrict__ H4 = (const float4*)H;
  int    cur = start, prev = start, plen = 1;
  double min_sim = 1e9;
  bool   detected = false;
  int    aborts = 0, restarts = 0;
  for (int step = 0; step < WALK_LEN; ++step) {
    uint32_t nk0 = 0u, nk1 = 0u; tf2x32(key0, key1, nk0, nk1);
    uint32_t ks0 = 0u, ks1 = 1u; tf2x32(key0, key1, ks0, ks1);
    uint32_t kr0 = 0u, kr1 = 2u; tf2x32(key0, key1, kr0, kr1);
    const double ncur = sqrt(sumsq[cur]) + 1e-8;
    double a[16];
    {
      const float4* rc = H4 + ((size_t)cur << 8);
#pragma unroll
      for (int k = 0; k < 4; ++k) {
        float4 x = rc[lane + (k << 6)];
        a[4*k+0] = x.x; a[4*k+1] = x.y; a[4*k+2] = x.z; a[4*k+3] = x.w;
      }
    }
    double my_sim = 0.0;
    for (int jj = 0; jj < 33; ++jj) {
      const int idx = cur - HALF_WIN + jj;
      if (jj == HALF_WIN || idx < 0 || idx >= seq_len) continue;
      const float4* rb = H4 + ((size_t)idx << 8);
      double acc = 0.0;
#pragma unroll
      for (int k = 0; k < 4; ++k) {
        float4 x = rb[lane + (k << 6)];
        acc += a[4*k+0] * (double)x.x + a[4*k+1] * (double)x.y
             + a[4*k+2] * (double)x.z + a[4*k+3] * (double)x.w;
      }
#pragma unroll
      for (int off = 32; off; off >>= 1) acc += __shfl_xor(acc, off);
      const double s = acc / (ncur * (sqrt(sumsq[idx]) + 1e-8));
      if (lane == jj) my_sim = s;
    }
    bool found = false; int fails = 0, p = 0, cand = 0;
    const int  myidx   = cur - HALF_WIN + lane;
    const bool myvalid = (lane < 33) && (lane != HALF_WIN) &&
                         (myidx >= 0) && (myidx < seq_len);
    for (int at = 0; at < 3; ++at) {
      uint32_t s0 = 0u, s1 = (uint32_t)at; tf2x32(ks0, ks1, s0, s1);
      double z; int bi;
      if (myvalid) {
        const uint32_t bits = tf_fold(s0, s1, 0u, (uint32_t)lane);
        const uint32_t fb   = (bits >> 9) | 0x3f800000u;
        const float    f    = __uint_as_float(fb) - 1.0f;
        const float    u    = (f > 0.0f) ? f : 1.1754943508222875e-38f;
        const double   g    = -log(-log((double)u));
        z  = g + 5.0 * my_sim;
        bi = lane;
      } else { z = -1e300; bi = 1000; }
#pragma unroll
      for (int off = 32; off; off >>= 1) {
        const double oz = __shfl_xor(z, off);
        const int    oi = __shfl_xor(bi, off);
        if (oz > z || (oz == z && oi < bi)) { z = oz; bi = oi; }
      }
      p    = bi;
      cand = cur - HALF_WIN + p;
      bool ok;
      if (plen < 2) ok = true;
      else {
        const float na = (float)sumsq[prev], nb = (float)sumsq[cur],
                    nc = (float)sumsq[cand];
        const float tr  = (na * nb * nc) /
                          ((na + 1e-8f) * (nb + 1e-8f) * (nc + 1e-8f));
        const float dev = fabsf(tr - rintf(tr));
        ok = (dev <= 0.1f) && (tr <= 1.5f);
      }
      if (ok) { found = true; break; }
      ++fails;
    }
    aborts += fails;
    if (found) {
      const double sim = __shfl(my_sim, p);
      const double nm  = fmin(min_sim, sim);
      const bool closed = (cand == start) && (plen > 2);
      prev = cur; cur = cand; plen += 1; min_sim = nm;
      if (closed) { if (nm < 0.1) detected = true; break; }
    } else {
      ++restarts;
      uint32_t h0 = 0u, h1 = 0u; tf2x32(kr0, kr1, h0, h1);
      uint32_t l0 = 0u, l1 = 1u; tf2x32(kr0, kr1, l0, l1);
      const uint32_t hi = tf_fold(h0, h1, 0u, 0u);
      const uint32_t lo = tf_fold(l0, l1, 0u, 0u);
      const uint32_t span = (uint32_t)nv;
      uint32_t mult = (65536u % span); mult = (mult * mult) % span;
      const uint32_t r = ((hi % span) * mult + (lo % span)) % span;
      const int node = viol[r];
      cur = node; prev = node; plen = 1;
    }
    key0 = nk0; key1 = nk1;
  }
  if (lane == 0) {
    if (detected)      atomicOr(&out[v], 1);
    if (aborts != 0)   atomicAdd(&out[nv], aborts);
    if (restarts != 0) atomicAdd(&out[nv + 1], restarts);
  }
}

extern "C" void kernel_launch(void* const* d_in, const int* in_sizes, int n_in,
                              void* d_out, int out_size, void* d_ws, size_t ws_size,
                              hipStream_t stream) {
  const float* H    = (const float*)d_in[0];
  const int*   viol = (const int*)d_in[1];
  const int    nv      = in_sizes[1];
  const int    seq_len = in_sizes[0] / HID;
  const int    nwalks  = nv * NUM_WALKS;

  double* sumsq = (double*)d_ws;                       // seq_len * 8 B
  double* Etab  = (double*)((char*)d_ws + (size_t)seq_len * sizeof(double));
  const size_t need = (size_t)seq_len * sizeof(double)
                    + (size_t)seq_len * 33 * sizeof(double);

  const int wblocks = (nwalks + 3) / 4;

  if (ws_size >= need) {
    const int blocks = (seq_len + CENTERS - 1) / CENTERS;   // 512 @ 8192
    band_fused_kernel<<<blocks, 512, 0, stream>>>(H, sumsq, Etab,
                                                  (int*)d_out, out_size,
                                                  seq_len);
    walk_pre_kernel<<<wblocks, 256, 0, stream>>>(Etab, sumsq, viol,
                                                 (int*)d_out, nv, seq_len);
  } else {
    const int blocks = (seq_len + 3) / 4;
    rowsq_kernel<<<blocks, 256, 0, stream>>>(H, sumsq, (int*)d_out,
                                             out_size, seq_len);
    walk_ref_kernel<<<wblocks, 256, 0, stream>>>(H, viol, sumsq,
                                                 (int*)d_out, nv, seq_len);
  }
}

// Round 10
// 60.582 us; speedup vs baseline: 1.2838x; 1.0349x over previous
//
#include <hip/hip_runtime.h>
#include <stdint.h>
#include <math.h>

// ---------------------------------------------------------------------------
// SparseExplorerRouting, round 13.
//
// Carried facts (best = R12 62.7us; R1-R3/R5/R9-R12 PASSED absmax 0):
//   * jax_threefry_partitionable=True counter scheme; key(42) -> (0,42);
//     walk (v,w) = split child v*5+w; per-step children ctr (0,{0,1,2}).
//   * output int32 {flags[1024], sum_aborts, sum_restarts}.
//   * E-table argmax(E/w) trick, w=-log(u); minE<e^0.5 == min_sim<0.1.
//   * PRECISION: reference computes -log(u) in f32; HW v_log_f32 (~6e-8)
//     proven safe on HW (R12 absmax 0).
//   * R12 walk_pre = 36.8us = 16.6 base + ~20 prologue; with log now cheap
//     the prologue cost is the 8 PER-LANE threefry folds (VALU), not the
//     wave-uniform SALU chains (free, parallel pipe) and not the log.
//   * R5 band (512thr, unrolled d-loop, 131KB LDS) = 25.9us: KEEPER
//     (R7 MFMA and R10 K-split both failed to beat it).
//   * Only 32 w-slots per step are consumed: j in {0..32}\{16}.
//
// Round 13 change (walk prologue only; band/hot-loop semantics untouched):
//   * STEP-PAIRED prologue: one 64-lane fold produces TWO steps' w --
//     lanes 0..31 = step 2t slots, lanes 32..63 = step 2t+1 slots
//     (slot sl -> j = sl+(sl>15); same counters (0,j), same keys via 2-op
//     select => identical doubles). 8 folds+logs -> 4. invwp[4] (8 VGPR).
//   * Hot loop: w via one __shfl(invwp[s>>1], ((s&1)<<5)+sl) per step
//     (static array index; 8 bpermutes per walk, negligible).
//   * Cold paths (at>0, restart) recompute from saved k0s/k1s: unchanged.
// ---------------------------------------------------------------------------

#define HID        1024
#define NUM_WALKS  5
#define WALK_LEN   8
#define HALF_WIN   16
#define E_THRESH   1.6487212707001282   // exp(0.5) = exp(5 * BIRTH_DEATH_EPS)

#define CENTERS    16                   // centers per band block
#define SROWS      32                   // staged rows = CENTERS + 16 halo

__device__ __forceinline__ void tf2x32(uint32_t k0, uint32_t k1,
                                       uint32_t& x0, uint32_t& x1) {
  uint32_t ks2 = k0 ^ k1 ^ 0x1BD11BDAu;
  x0 += k0; x1 += k1;
#define TFR(r) { x0 += x1; x1 = (x1 << (r)) | (x1 >> (32 - (r))); x1 ^= x0; }
  TFR(13) TFR(15) TFR(26) TFR(6)
  x0 += k1;  x1 += ks2 + 1u;
  TFR(17) TFR(29) TFR(16) TFR(24)
  x0 += ks2; x1 += k0 + 2u;
  TFR(13) TFR(15) TFR(26) TFR(6)
  x0 += k0;  x1 += k1 + 3u;
  TFR(17) TFR(29) TFR(16) TFR(24)
  x0 += k1;  x1 += ks2 + 4u;
  TFR(13) TFR(15) TFR(26) TFR(6)
  x0 += ks2; x1 += k0 + 5u;
#undef TFR
}

__device__ __forceinline__ uint32_t tf_fold(uint32_t k0, uint32_t k1,
                                            uint32_t c0, uint32_t c1) {
  tf2x32(k0, k1, c0, c1);
  return c0 ^ c1;
}

// w = -log(u), u = k*2^-23 (k = bits>>9), via HW v_log_f32.
// (float)k exact (k<2^24); *2^-23 exact; log2f ~1ulp (6e-8 rel) -- proven
// safe on HW (R12 absmax 0).
__device__ __forceinline__ double fast_neg_log(uint32_t bits) {
  const uint32_t k = bits >> 9;
  if (k == 0) return 87.33654475055310899;    // -log(2^-126) clamp
  const float u  = (float)k * 1.1920928955078125e-7f;   // k * 2^-23, exact
  const float l2 = __log2f(u);                          // v_log_f32
  return (double)l2 * -0.6931471805599453;
}

// ---- fused band + rowsq + d_out zeroing (R5 512-thread form, verbatim) -----
__global__ __launch_bounds__(512) void band_fused_kernel(
    const float* __restrict__ H, double* __restrict__ sumsq,
    double* __restrict__ E, int* __restrict__ out, int out_n, int seq_len) {
  __shared__ __align__(16) float  tile[SROWS][HID];   // 128 KB
  __shared__ double ssq[SROWS];

  if (blockIdx.x == 0) {                 // fold d_out zeroing in (dispatch
    for (int t = threadIdx.x; t < out_n; t += 512) out[t] = 0;   // ordering
  }                                      // guarantees walk sees zeros)

  int wg = blockIdx.x;
  {
    const int nwg = gridDim.x;           // bijective XCD swizzle (nwg%8==0)
    if ((nwg & 7) == 0) wg = (wg & 7) * (nwg >> 3) + (wg >> 3);
  }
  const int wid  = (int)(threadIdx.x >> 6);   // 0..7
  const int lane = (int)(threadIdx.x & 63);
  const int i0   = wg * CENTERS;
  const float4* __restrict__ H4 = (const float4*)H;

  // ---- stage 4 rows per wave + sumsq (same order as old rowsq) ----
#pragma unroll
  for (int rr = 0; rr < 4; ++rr) {
    const int local = wid * 4 + rr;      // wave-uniform
    const int row   = i0 + local;
    if (row < seq_len) {
      const float4* src = H4 + ((size_t)row << 8);
      float4* dst = (float4*)&tile[local][0];
      double acc = 0.0;
#pragma unroll
      for (int k = 0; k < 4; ++k) {
        float4 x = src[lane + (k << 6)];
        dst[lane + (k << 6)] = x;
        acc += (double)x.x * x.x + (double)x.y * x.y
             + (double)x.z * x.z + (double)x.w * x.w;
      }
#pragma unroll
      for (int off = 32; off; off >>= 1) acc += __shfl_xor(acc, off);
      if (lane == 0) {
        ssq[local] = acc;
        if (local < CENTERS) sumsq[row] = acc;   // each row owned by 1 block
      }
    }
  }
  __syncthreads();

  // ---- 2 centers per wave, 16 forward dots each, from LDS ----
#pragma unroll
  for (int cc = 0; cc < 2; ++cc) {
    const int cl = wid * 2 + cc;         // 0..15, wave-uniform
    const int i  = i0 + cl;
    if (i >= seq_len) continue;

    double a[16];
    {
      const float4* rc = (const float4*)&tile[cl][0];
#pragma unroll
      for (int k = 0; k < 4; ++k) {
        float4 x = rc[lane + (k << 6)];
        a[4*k+0] = x.x; a[4*k+1] = x.y; a[4*k+2] = x.z; a[4*k+3] = x.w;
      }
    }
    const double ni = sqrt(ssq[cl]) + 1e-8;

    // d-loop fully unrolled: p[] indices static -> registers, no scratch.
    // Halo garbage (i+d >= seq_len) stays segregated per-d and never
    // reaches the guarded write. Bit-identical valid E.
    double p[16];
#pragma unroll
    for (int d = 0; d < 16; ++d) p[d] = 0.0;
#pragma unroll
    for (int d = 1; d <= 16; ++d) {
      const float4* rb = (const float4*)&tile[cl + d][0];
#pragma unroll
      for (int k = 0; k < 4; ++k) {
        float4 x = rb[lane + (k << 6)];
        p[d-1] += a[4*k+0] * (double)x.x + a[4*k+1] * (double)x.y
                + a[4*k+2] * (double)x.z + a[4*k+3] * (double)x.w;
      }
    }

    // multi-value reduce-scatter: value bit3..0 <- lane bit5..2
#pragma unroll
    for (int v = 0; v < 8; ++v) {                     // stage xor 32
      double send = (lane & 32) ? p[v] : p[v+8];
      double recv = __shfl_xor(send, 32);
      double mine = (lane & 32) ? p[v+8] : p[v];
      p[v] = mine + recv;
    }
#pragma unroll
    for (int v = 0; v < 4; ++v) {                     // stage xor 16
      double send = (lane & 16) ? p[v] : p[v+4];
      double recv = __shfl_xor(send, 16);
      double mine = (lane & 16) ? p[v+4] : p[v];
      p[v] = mine + recv;
    }
#pragma unroll
    for (int v = 0; v < 2; ++v) {                     // stage xor 8
      double send = (lane & 8) ? p[v] : p[v+2];
      double recv = __shfl_xor(send, 8);
      double mine = (lane & 8) ? p[v+2] : p[v];
      p[v] = mine + recv;
    }
    {                                                 // stage xor 4
      double send = (lane & 4) ? p[0] : p[1];
      double recv = __shfl_xor(send, 4);
      double mine = (lane & 4) ? p[1] : p[0];
      p[0] = mine + recv;
    }
    p[0] += __shfl_xor(p[0], 2);                      // stage xor 2
    p[0] += __shfl_xor(p[0], 1);                      // stage xor 1

    const int v = ((lane >> 2) & 1) | (((lane >> 3) & 1) << 1)
                | (((lane >> 4) & 1) << 2) | (((lane >> 5) & 1) << 3);
    const int d = v + 1;
    if ((lane & 3) == 0 && i + d < seq_len) {
      const double s  = p[0] / (ni * (sqrt(ssq[cl + d]) + 1e-8));
      const double Ev = exp(5.0 * s);
      E[(size_t)i * 33 + 16 + d]       = Ev;
      E[(size_t)(i + d) * 33 + 16 - d] = Ev;
    }
  }
}

// ---- per-row sum of squares (f64) + d_out zeroing (fallback tier only) -----
__global__ __launch_bounds__(256) void rowsq_kernel(
    const float* __restrict__ H, double* __restrict__ sumsq,
    int* __restrict__ out, int out_n, int seq_len) {
  if (blockIdx.x == 0) {
    for (int t = threadIdx.x; t < out_n; t += 256) out[t] = 0;
  }
  const int row  = (int)((blockIdx.x * blockDim.x + threadIdx.x) >> 6);
  const int lane = threadIdx.x & 63;
  if (row >= seq_len) return;
  const float4* r = (const float4*)(H + (size_t)row * HID);
  double acc = 0.0;
#pragma unroll
  for (int k = 0; k < 4; ++k) {
    float4 x = r[lane + (k << 6)];
    acc += (double)x.x * x.x + (double)x.y * x.y
         + (double)x.z * x.z + (double)x.w * x.w;
  }
#pragma unroll
  for (int off = 32; off; off >>= 1) acc += __shfl_xor(acc, off);
  if (lane == 0) sumsq[row] = acc;
}

// ---- walk kernel: step-paired prologue w, fully unrolled steps -------------
__global__ __launch_bounds__(256) void walk_pre_kernel(
    const double* __restrict__ E, const double* __restrict__ sumsq,
    const int* __restrict__ viol, int* __restrict__ out,
    int nv, int seq_len) {
  int wave = (int)((blockIdx.x * blockDim.x + threadIdx.x) >> 6);
  const int lane = threadIdx.x & 63;
  if (wave >= nv * NUM_WALKS) return;
  wave = __builtin_amdgcn_readfirstlane(wave);
  const int v     = wave / NUM_WALKS;
  const int start = viol[v];

  uint32_t key0 = 0u, key1 = (uint32_t)wave;
  tf2x32(0u, 42u, key0, key1);
  key0 = __builtin_amdgcn_readfirstlane(key0);
  key1 = __builtin_amdgcn_readfirstlane(key1);

  // ---- key chain (wave-uniform SALU, saved for cold paths) ----
  uint32_t k0s[WALK_LEN], k1s[WALK_LEN];
#pragma unroll
  for (int s = 0; s < WALK_LEN; ++s) {
    k0s[s] = key0; k1s[s] = key1;
    uint32_t nk0 = 0u, nk1 = 0u; tf2x32(key0, key1, nk0, nk1);
    key0 = __builtin_amdgcn_readfirstlane(nk0);
    key1 = __builtin_amdgcn_readfirstlane(nk1);
  }

  // ---- STEP-PAIRED prologue: 4 per-lane folds produce all 8 steps' w ----
  // lanes 0..31: step 2t, slot sl = lane;  lanes 32..63: step 2t+1, slot
  // sl = lane-32;  slot sl -> candidate j = sl + (sl>15)  (j=16 == cur is
  // never consumed). Counters (0,j) and per-half keys identical to the
  // per-step form => identical doubles, just placed 2-steps-per-wave.
  const int  sl_mine = lane & 31;
  const uint32_t jpk = (uint32_t)(sl_mine + (sl_mine > 15 ? 1 : 0));
  double invwp[WALK_LEN / 2];
#pragma unroll
  for (int t = 0; t < WALK_LEN / 2; ++t) {
    uint32_t ksA0 = 0u, ksA1 = 1u; tf2x32(k0s[2*t],   k1s[2*t],   ksA0, ksA1);
    uint32_t sA0  = 0u, sA1  = 0u; tf2x32(ksA0, ksA1, sA0, sA1);   // at=0
    uint32_t ksB0 = 0u, ksB1 = 1u; tf2x32(k0s[2*t+1], k1s[2*t+1], ksB0, ksB1);
    uint32_t sB0  = 0u, sB1  = 0u; tf2x32(ksB0, ksB1, sB0, sB1);   // at=0
    const uint32_t s0 = (lane & 32) ? sB0 : sA0;   // 2-op per-lane select
    const uint32_t s1 = (lane & 32) ? sB1 : sA1;
    const uint32_t bits = tf_fold(s0, s1, 0u, jpk);
    invwp[t] = 1.0 / fast_neg_log(bits);
  }

  // consuming lane j reads slot sl = j - (j>16) from half (step&1)
  const int sl_use = (lane < 33 && lane != HALF_WIN)
                   ? (lane - (lane > HALF_WIN)) : 0;

  int    cur = start, prev = start, plen = 1;
  double minE = 1e300;
  bool   detected = false;
  int    aborts = 0, restarts = 0;
  // carried |h|^2 of prev / cur (identical doubles to sumsq[] entries)
  double na_d = sumsq[start], nb_d = na_d;

#pragma unroll
  for (int step = 0; step < WALK_LEN; ++step) {
    const int  myidx   = cur - HALF_WIN + lane;
    const bool myvalid = (lane < 33) && (lane != HALF_WIN) &&
                         (myidx >= 0) && (myidx < seq_len);
    const int  clipped = myidx < 0 ? 0 : (myidx >= seq_len ? seq_len - 1 : myidx);
    const double Ej = E[(size_t)cur * 33 + (lane < 33 ? lane : 0)];
    const double sq_win = sumsq[clipped];   // window |h|^2, issued with Ej
    // my step's 1/w: one bpermute from the paired prologue value
    const double invw_s = __shfl(invwp[step >> 1],
                                 ((step & 1) << 5) + sl_use);

    bool found = false; int fails = 0, p = 0, cand = 0;
    double nc_d = 0.0;
    for (int at = 0; at < 3; ++at) {
      double f; int bi;
      if (myvalid) {
        if (at == 0) {
          f = Ej * invw_s;      // hot path: no threefry, no log, no div
        } else {                // cold path (rare): recompute from saved key
          uint32_t ks0 = 0u, ks1 = 1u; tf2x32(k0s[step], k1s[step], ks0, ks1);
          uint32_t s0 = 0u, s1 = (uint32_t)at; tf2x32(ks0, ks1, s0, s1);
          const uint32_t bits = tf_fold(s0, s1, 0u, (uint32_t)lane);
          f = Ej / fast_neg_log(bits);
        }
        bi = lane;
      } else { f = -1.0; bi = 1000; }
#pragma unroll
      for (int off = 32; off; off >>= 1) {
        const double of = __shfl_xor(f, off);
        const int    oi = __shfl_xor(bi, off);
        if (of > f || (of == f && oi < bi)) { f = of; bi = oi; }
      }
      p    = bi;
      cand = cur - HALF_WIN + p;
      nc_d = __shfl(sq_win, p);     // == sumsq[cand], no dependent load
      bool ok;
      if (plen < 2) ok = true;
      else {
        const float na = (float)na_d, nb = (float)nb_d, nc = (float)nc_d;
        const float tr  = (na * nb * nc) /
                          ((na + 1e-8f) * (nb + 1e-8f) * (nc + 1e-8f));
        const float dev = fabsf(tr - rintf(tr));
        ok = (dev <= 0.1f) && (tr <= 1.5f);
      }
      if (ok) { found = true; break; }
      ++fails;
    }
    aborts += fails;

    if (found) {
      const double Ewin = __shfl(Ej, p);
      minE = fmin(minE, Ewin);
      const bool closed = (cand == start) && (plen > 2);
      prev = cur; cur = cand; plen += 1;
      na_d = nb_d; nb_d = nc_d;
      if (closed) { if (minE < E_THRESH) detected = true; break; }
    } else {
      ++restarts;                 // rare path: restart chain from saved key
      uint32_t kr0 = 0u, kr1 = 2u; tf2x32(k0s[step], k1s[step], kr0, kr1);
      uint32_t h0 = 0u, h1 = 0u; tf2x32(kr0, kr1, h0, h1);
      uint32_t l0 = 0u, l1 = 1u; tf2x32(kr0, kr1, l0, l1);
      const uint32_t hi = tf_fold(h0, h1, 0u, 0u);
      const uint32_t lo = tf_fold(l0, l1, 0u, 0u);
      const uint32_t span = (uint32_t)nv;
      uint32_t mult = (65536u % span); mult = (mult * mult) % span;
      const uint32_t r = ((hi % span) * mult + (lo % span)) % span;
      const int node = viol[r];
      cur = node; prev = node; plen = 1;
      na_d = sumsq[node]; nb_d = na_d;
    }
  }

  if (lane == 0) {
    if (detected)      atomicOr(&out[v], 1);
    if (aborts != 0)   atomicAdd(&out[nv], aborts);
    if (restarts != 0) atomicAdd(&out[nv + 1], restarts);
  }
}

// ---- fallback: round-1 in-walk dot kernel (only if ws too small) -----------
__global__ __launch_bounds__(256) void walk_ref_kernel(
    const float* __restrict__ H, const int* __restrict__ viol,
    const double* __restrict__ sumsq, int* __restrict__ out,
    int nv, int seq_len) {
  const int wave = (int)((blockIdx.x * blockDim.x + threadIdx.x) >> 6);
  const int lane = threadIdx.x & 63;
  if (wave >= nv * NUM_WALKS) return;
  const int v     = wave / NUM_WALKS;
  const int start = viol[v];
  uint32_t key0 = 0u, key1 = (uint32_t)wave;
  tf2x32(0u, 42u, key0, key1);
  const float4* __restrict__ H4 = (const float4*)H;
  int    cur = start, prev = start, plen = 1;
  double min_sim = 1e9;
  bool   detected = false;
  int    aborts = 0, restarts = 0;
  for (int step = 0; step < WALK_LEN; ++step) {
    uint32_t nk0 = 0u, nk1 = 0u; tf2x32(key0, key1, nk0, nk1);
    uint32_t ks0 = 0u, ks1 = 1u; tf2x32(key0, key1, ks0, ks1);
    uint32_t kr0 = 0u, kr1 = 2u; tf2x32(key0, key1, kr0, kr1);
    const double ncur = sqrt(sumsq[cur]) + 1e-8;
    double a[16];
    {
      const float4* rc = H4 + ((size_t)cur << 8);
#pragma unroll
      for (int k = 0; k < 4; ++k) {
        float4 x = rc[lane + (k << 6)];
        a[4*k+0] = x.x; a[4*k+1] = x.y; a[4*k+2] = x.z; a[4*k+3] = x.w;
      }
    }
    double my_sim = 0.0;
    for (int jj = 0; jj < 33; ++jj) {
      const int idx = cur - HALF_WIN + jj;
      if (jj == HALF_WIN || idx < 0 || idx >= seq_len) continue;
      const float4* rb = H4 + ((size_t)idx << 8);
      double acc = 0.0;
#pragma unroll
      for (int k = 0; k < 4; ++k) {
        float4 x = rb[lane + (k << 6)];
        acc += a[4*k+0] * (double)x.x + a[4*k+1] * (double)x.y
             + a[4*k+2] * (double)x.z + a[4*k+3] * (double)x.w;
      }
#pragma unroll
      for (int off = 32; off; off >>= 1) acc += __shfl_xor(acc, off);
      const double s = acc / (ncur * (sqrt(sumsq[idx]) + 1e-8));
      if (lane == jj) my_sim = s;
    }
    bool found = false; int fails = 0, p = 0, cand = 0;
    const int  myidx   = cur - HALF_WIN + lane;
    const bool myvalid = (lane < 33) && (lane != HALF_WIN) &&
                         (myidx >= 0) && (myidx < seq_len);
    for (int at = 0; at < 3; ++at) {
      uint32_t s0 = 0u, s1 = (uint32_t)at; tf2x32(ks0, ks1, s0, s1);
      double z; int bi;
      if (myvalid) {
        const uint32_t bits = tf_fold(s0, s1, 0u, (uint32_t)lane);
        const uint32_t fb   = (bits >> 9) | 0x3f800000u;
        const float    f    = __uint_as_float(fb) - 1.0f;
        const float    u    = (f > 0.0f) ? f : 1.1754943508222875e-38f;
        const double   g    = -log(-log((double)u));
        z  = g + 5.0 * my_sim;
        bi = lane;
      } else { z = -1e300; bi = 1000; }
#pragma unroll
      for (int off = 32; off; off >>= 1) {
        const double oz = __shfl_xor(z, off);
        const int    oi = __shfl_xor(bi, off);
        if (oz > z || (oz == z && oi < bi)) { z = oz; bi = oi; }
      }
      p    = bi;
      cand = cur - HALF_WIN + p;
      bool ok;
      if (plen < 2) ok = true;
      else {
        const float na = (float)sumsq[prev], nb = (float)sumsq[cur],
                    nc = (float)sumsq[cand];
        const float tr  = (na * nb * nc) /
                          ((na + 1e-8f) * (nb + 1e-8f) * (nc + 1e-8f));
        const float dev = fabsf(tr - rintf(tr));
        ok = (dev <= 0.1f) && (tr <= 1.5f);
      }
      if (ok) { found = true; break; }
      ++fails;
    }
    aborts += fails;
    if (found) {
      const double sim = __shfl(my_sim, p);
      const double nm  = fmin(min_sim, sim);
      const bool closed = (cand == start) && (plen > 2);
      prev = cur; cur = cand; plen += 1; min_sim = nm;
      if (closed) { if (nm < 0.1) detected = true; break; }
    } else {
      ++restarts;
      uint32_t h0 = 0u, h1 = 0u; tf2x32(kr0, kr1, h0, h1);
      uint32_t l0 = 0u, l1 = 1u; tf2x32(kr0, kr1, l0, l1);
      const uint32_t hi = tf_fold(h0, h1, 0u, 0u);
      const uint32_t lo = tf_fold(l0, l1, 0u, 0u);
      const uint32_t span = (uint32_t)nv;
      uint32_t mult = (65536u % span); mult = (mult * mult) % span;
      const uint32_t r = ((hi % span) * mult + (lo % span)) % span;
      const int node = viol[r];
      cur = node; prev = node; plen = 1;
    }
    key0 = nk0; key1 = nk1;
  }
  if (lane == 0) {
    if (detected)      atomicOr(&out[v], 1);
    if (aborts != 0)   atomicAdd(&out[nv], aborts);
    if (restarts != 0) atomicAdd(&out[nv + 1], restarts);
  }
}

extern "C" void kernel_launch(void* const* d_in, const int* in_sizes, int n_in,
                              void* d_out, int out_size, void* d_ws, size_t ws_size,
                              hipStream_t stream) {
  const float* H    = (const float*)d_in[0];
  const int*   viol = (const int*)d_in[1];
  const int    nv      = in_sizes[1];
  const int    seq_len = in_sizes[0] / HID;
  const int    nwalks  = nv * NUM_WALKS;

  double* sumsq = (double*)d_ws;                       // seq_len * 8 B
  double* Etab  = (double*)((char*)d_ws + (size_t)seq_len * sizeof(double));
  const size_t need = (size_t)seq_len * sizeof(double)
                    + (size_t)seq_len * 33 * sizeof(double);

  const int wblocks = (nwalks + 3) / 4;

  if (ws_size >= need) {
    const int blocks = (seq_len + CENTERS - 1) / CENTERS;   // 512 @ 8192
    band_fused_kernel<<<blocks, 512, 0, stream>>>(H, sumsq, Etab,
                                                  (int*)d_out, out_size,
                                                  seq_len);
    walk_pre_kernel<<<wblocks, 256, 0, stream>>>(Etab, sumsq, viol,
                                                 (int*)d_out, nv, seq_len);
  } else {
    const int blocks = (seq_len + 3) / 4;
    rowsq_kernel<<<blocks, 256, 0, stream>>>(H, sumsq, (int*)d_out,
                                             out_size, seq_len);
    walk_ref_kernel<<<wblocks, 256, 0, stream>>>(H, viol, sumsq,
                                                 (int*)d_out, nv, seq_len);
  }
}